// Round 6
// baseline (420.716 us; speedup 1.0000x reference)
//
#include <hip/hip_runtime.h>
#include <hip/hip_fp16.h>

#define N_NODES 100000
#define N_EDGES 1600000
#define D_IN 25
#define D_OUT 50
// scatter granularity: coarse buckets of 256 dsts (good write coalescing)
#define NBKT_C 391      // ceil(100000/256)
#define BSTR_C 4800     // mean 4096 + ~11 sigma
#define BSTR_S 5568     // sorted stride: BSTR_C + 256*3 padding (hard bound)
// gat granularity: 64 dsts per block; 4 gat blocks per coarse bucket
#define DPB 64
#define NBKT_F 1563     // ceil(100000/64)
#define EPB 8192        // edges per block in scatter pass
#define NBLK_E 196      // ceil(N_EDGES/EPB)

typedef __attribute__((ext_vector_type(8))) _Float16 half8;
typedef __attribute__((ext_vector_type(2))) _Float16 h2;
typedef __attribute__((ext_vector_type(4))) float float4v;
typedef __attribute__((ext_vector_type(2))) float f2;

__device__ __forceinline__ float lrelu(float x, float a) { return fmaxf(x, a * x); }
__device__ __forceinline__ h2 bch2(unsigned u) { return __builtin_bit_cast(h2, u); }

// ---------------- fused bucket scatter: LDS hist -> global reserve -> write ------
// Coarse 256-dst buckets keep per-block per-bucket runs ~21 edges = 84B
// contiguous (fine 64-dst buckets measured 143MB HBM writes for a 19MB payload).
__global__ __launch_bounds__(256) void bkt_scatter_kernel(
    const int* __restrict__ eip, const int* __restrict__ eis, const int* __restrict__ eiv,
    unsigned* __restrict__ bcur3, unsigned* __restrict__ bucketedC)
{
    int t = blockIdx.y;
    const int* ei = (t == 0) ? eip : ((t == 1) ? eis : eiv);
    unsigned* bcur = bcur3 + t * NBKT_C;
    unsigned* bucketed = bucketedC + (size_t)t * NBKT_C * BSTR_C;
    __shared__ unsigned h[NBKT_C];
    __shared__ unsigned cur[NBKT_C];
    int tid = threadIdx.x;
    for (int b = tid; b < NBKT_C; b += 256) h[b] = 0;
    __syncthreads();
#pragma unroll
    for (int i = 0; i < EPB / 1024; ++i) {
        int e = blockIdx.x * EPB + (i * 256 + tid) * 4;
        if (e < N_EDGES) {               // N_EDGES % 4 == 0: whole int4 valid
            int4 d4 = *(const int4*)&ei[N_EDGES + e];
            atomicAdd(&h[(unsigned)d4.x >> 8], 1u);
            atomicAdd(&h[(unsigned)d4.y >> 8], 1u);
            atomicAdd(&h[(unsigned)d4.z >> 8], 1u);
            atomicAdd(&h[(unsigned)d4.w >> 8], 1u);
        }
    }
    __syncthreads();
    for (int b = tid; b < NBKT_C; b += 256)
        cur[b] = (unsigned)b * BSTR_C + (h[b] ? atomicAdd(&bcur[b], h[b]) : 0u);
    __syncthreads();
#pragma unroll
    for (int i = 0; i < EPB / 1024; ++i) {
        int e = blockIdx.x * EPB + (i * 256 + tid) * 4;
        if (e < N_EDGES) {
            int4 s4 = *(const int4*)&ei[e];
            int4 d4 = *(const int4*)&ei[N_EDGES + e];
            int ss[4] = {s4.x, s4.y, s4.z, s4.w};
            int dd[4] = {d4.x, d4.y, d4.z, d4.w};
#pragma unroll
            for (int k = 0; k < 4; ++k) {
                unsigned d = (unsigned)dd[k];
                unsigned b = d >> 8;
                unsigned r = atomicAdd(&cur[b], 1u);
                if (r < (b + 1u) * BSTR_C)   // overflow guard (11-sigma margin)
                    bucketed[r] = ((d & 255u) << 17) | (unsigned)ss[k];
            }
        }
    }
}

// ---------------- counting sort: coarse bucket -> per-dst lists + offsets --------
// One block per (coarse bucket, tag). Full 256-dst sort in LDS, per-dst lists
// padded to x4 with flagged dummy entries (index 0, weight forced to 0 in gat),
// written out coalesced. dstart[257] per coarse bucket -> gat needs NO prologue.
__global__ __launch_bounds__(256) void bkt_sort_kernel(
    const unsigned* __restrict__ bucketedC, const unsigned* __restrict__ bcur3,
    unsigned* __restrict__ srcsS, unsigned* __restrict__ dstartAll)
{
    int tag = blockIdx.y, cb = blockIdx.x;
    const unsigned* in = bucketedC + ((size_t)tag * NBKT_C + cb) * BSTR_C;
    unsigned* outp = srcsS + (size_t)tag * NBKT_C * BSTR_S + (size_t)cb * BSTR_S;
    unsigned* dstart = dstartAll + ((size_t)tag * NBKT_C + cb) * 257;
    __shared__ unsigned hist[256];
    __shared__ unsigned cur[256];
    __shared__ __align__(16) unsigned sbuf[BSTR_S];
    __shared__ unsigned totS;
    int tid = threadIdx.x;
    unsigned cnt = bcur3[tag * NBKT_C + cb];
    if (cnt > BSTR_C) cnt = BSTR_C;
    hist[tid] = 0;
    __syncthreads();
    for (unsigned i = tid; i < cnt; i += 256) atomicAdd(&hist[in[i] >> 17], 1u);
    __syncthreads();
    unsigned c = hist[tid];
    unsigned pc = (c + 3u) & ~3u;        // pad each dst's list to multiple of 4
    hist[tid] = pc;
    __syncthreads();
    for (int off = 1; off < 256; off <<= 1) {   // inclusive scan of padded counts
        unsigned v = (tid >= off) ? hist[tid - off] : 0u;
        __syncthreads();
        hist[tid] += v;
        __syncthreads();
    }
    unsigned excl = hist[tid] - pc;
    cur[tid] = excl;
    dstart[tid] = (unsigned)cb * BSTR_S + excl;   // absolute within-tag offset
    if (tid == 255) { dstart[256] = (unsigned)cb * BSTR_S + hist[255]; totS = hist[255]; }
    __syncthreads();
    for (unsigned i = tid; i < cnt; i += 256) {   // scatter into LDS sorted order
        unsigned w = in[i];
        unsigned r = atomicAdd(&cur[w >> 17], 1u);
        sbuf[r] = (w & 0x1FFFFu) << 3;            // pre-scaled uint4 row index
    }
    {
        const unsigned DUMMY = 0x80000000u;       // flagged, index 0 (valid row)
        for (unsigned k = c; k < pc; ++k) sbuf[excl + k] = DUMMY;  // disjoint slots
    }
    __syncthreads();
    unsigned tot = totS;                 // <= BSTR_S by construction
    for (unsigned i = tid; i < tot; i += 256) outp[i] = sbuf[i];
}

// ---------------- pack: head B-fragments (fp16) + transform weights + biases -----
// wpkAll: [0:25600) proj  [25600:40960) cls1  [40960:44032) cls2  [44032:44544) cls3
//         [44544:56832) transform 6 mats x 4 chunks x 512
// biasPad: [0:304) head; [304:688) transform 6 x 64
__device__ __forceinline__ void pack_seg(
    const float* __restrict__ W, unsigned short* __restrict__ outp,
    int K, int O, int NKS, int idx)
{
    int f = idx >> 9, r = idx & 511;
    int l = r >> 3, j = r & 7;
    int ot = f / NKS, ks = f - ot * NKS;
    int k = ks * 32 + (l >> 4) * 8 + j;
    int o = ot * 16 + (l & 15);
    float val = (k < K && o < O) ? W[k * O + o] : 0.f;
    outp[idx] = __half_as_ushort(__float2half_rn(val));
}

__global__ __launch_bounds__(256) void pack_all_kernel(
    const float* __restrict__ projW, const float* __restrict__ W1,
    const float* __restrict__ W2, const float* __restrict__ W3,
    const float* __restrict__ b0, const float* __restrict__ b1,
    const float* __restrict__ b2, const float* __restrict__ b3,
    const float* __restrict__ Wl0, const float* __restrict__ Wr0,
    const float* __restrict__ Wl1, const float* __restrict__ Wr1,
    const float* __restrict__ Wl2, const float* __restrict__ Wr2,
    const float* __restrict__ bl0, const float* __restrict__ br0,
    const float* __restrict__ bl1, const float* __restrict__ br1,
    const float* __restrict__ bl2, const float* __restrict__ br2,
    unsigned short* __restrict__ wpkAll, float* __restrict__ biasPad,
    __half* __restrict__ xl3)
{
    int gid = blockIdx.x * 256 + threadIdx.x;
    if (gid < 25600) pack_seg(projW, wpkAll, 150, 150, 5, gid);
    else if (gid < 40960) pack_seg(W1, wpkAll + 25600, 150, 75, 5, gid - 25600);
    else if (gid < 44032) pack_seg(W2, wpkAll + 40960, 75, 30, 3, gid - 40960);
    else if (gid < 44544) pack_seg(W3, wpkAll + 44032, 30, 2, 1, gid - 44032);
    else if (gid < 56832) {
        int t = gid - 44544;
        int mat = t >> 11, idx = t & 2047;
        const float* Wm = (mat == 0) ? Wl0 : (mat == 1) ? Wr0 : (mat == 2) ? Wl1
                        : (mat == 3) ? Wr1 : (mat == 4) ? Wl2 : Wr2;
        int ot = idx >> 9, r = idx & 511;
        int l = r >> 3, j = r & 7;
        int k = (l >> 4) * 8 + j;
        int o = ot * 16 + (l & 15);
        float val = (k < D_IN && o < D_OUT) ? Wm[k * D_OUT + o] : 0.f;
        wpkAll[44544 + t] = __half_as_ushort(__float2half_rn(val));
    } else if (gid < 57520) {
        int t = gid - 56832;
        float v;
        if (t < 304) {
            if (t < 160) v = (t < 150) ? b0[t] : 0.f;
            else if (t < 256) { int i = t - 160; v = (i < 75) ? b1[i] : 0.f; }
            else if (t < 288) { int i = t - 256; v = (i < 30) ? b2[i] : 0.f; }
            else { int i = t - 288; v = (i < 2) ? b3[i] : 0.f; }
        } else {
            int ii = t - 304;
            int mat = ii >> 6, o = ii & 63;
            const float* bm = (mat == 0) ? bl0 : (mat == 1) ? br0 : (mat == 2) ? bl1
                            : (mat == 3) ? br1 : (mat == 4) ? bl2 : br2;
            v = (o < D_OUT) ? bm[o] : 0.f;
        }
        biasPad[t] = v;
    } else if (gid < 57584) {
        // zero row at absolute row 3*N_NODES (kept for layout compat)
        xl3[(size_t)3 * N_NODES * 64 + (gid - 57520)] = __ushort_as_half((unsigned short)0);
    }
}

// ---------------- MFMA node transform: xl/xr (6 mats) via 16x16x32 f16 -----------
#define TSTR 32
#define OSTR 72

__global__ __launch_bounds__(256) void transform_mfma_kernel(
    const float* __restrict__ x,
    const unsigned short* __restrict__ wpkAll, const float* __restrict__ biasPad,
    __half* __restrict__ xl3, __half* __restrict__ xr3)
{
    __shared__ _Float16 sX[64 * TSTR];
    __shared__ _Float16 sO[4][16 * OSTR];
    int tid = threadIdx.x;
    int w = tid >> 6, l = tid & 63;
    int g0 = blockIdx.x * 64;
    for (int i = tid; i < 64 * D_IN; i += 256) {
        int r = i / D_IN, c = i - r * D_IN;
        int gr = g0 + r;
        sX[r * TSTR + c] = (gr < N_NODES) ? (_Float16)x[(size_t)gr * D_IN + c] : (_Float16)0.f;
    }
    for (int i = tid; i < 64 * 7; i += 256) {
        int r = i / 7, c = D_IN + (i - r * 7);
        sX[r * TSTR + c] = (_Float16)0.f;
    }
    __syncthreads();
    int lm = l & 15, q = l >> 4;
    half8 a = *(const half8*)(sX + (w * 16 + lm) * TSTR + q * 8);
    const unsigned short* wT = wpkAll + 44544;
#pragma unroll
    for (int mat = 0; mat < 6; ++mat) {
        float4v acc[4];
#pragma unroll
        for (int ot = 0; ot < 4; ++ot) {
            half8 b = *(const half8*)(wT + (mat * 4 + ot) * 512 + l * 8);
            float4v z = {0.f, 0.f, 0.f, 0.f};
            acc[ot] = __builtin_amdgcn_mfma_f32_16x16x32_f16(a, b, z, 0, 0, 0);
        }
#pragma unroll
        for (int ot = 0; ot < 4; ++ot) {
            float bv = biasPad[304 + mat * 64 + ot * 16 + lm];
#pragma unroll
            for (int r = 0; r < 4; ++r)
                sO[w][(q * 4 + r) * OSTR + ot * 16 + lm] = (_Float16)(acc[ot][r] + bv);
        }
        __half* dst = ((mat & 1) ? xr3 : xl3) + (size_t)(mat >> 1) * N_NODES * 64;
#pragma unroll
        for (int it = 0; it < 2; ++it) {
            int idx = it * 64 + l;
            int rr = idx >> 3, cc = idx & 7;
            int gr = g0 + w * 16 + rr;
            if (gr < N_NODES) {
                uint4 v = *(const uint4*)&sO[w][rr * OSTR + cc * 8];
                *(uint4*)&dst[(size_t)gr * 64 + cc * 8] = v;
            }
        }
    }
}

// ---------------- GATv2 aggregation over pre-sorted lists ------------------------
// One block per (64-dst group, tag). Depth-2 gather pipeline: per iteration,
// issue srcs chunk k+3, compute chunk k, refill gathers for chunk k+2 — keeps
// ~2 chunks of xl gathers in flight (round-5 counters: VALUBusy 60%, HBM 33%,
// occupancy flat vs resources => gather-latency-bound with 1-deep pipeline).
__device__ __forceinline__ float edge_score8(uint4 u, const h2* xr, const h2* at)
{
    const h2 k2 = {(_Float16)0.2f, (_Float16)0.2f};
    float acc = 0.f;
    unsigned uu[4] = {u.x, u.y, u.z, u.w};
#pragma unroll
    for (int i = 0; i < 4; ++i) {
        h2 m = bch2(uu[i]) + xr[i];
        m = __builtin_elementwise_max(m, m * k2);
        acc = __builtin_amdgcn_fdot2(m, at[i], acc, false);
    }
    return acc;
}
__device__ __forceinline__ void accum8v(f2* O, float w, uint4 u)
{
    unsigned uu[4] = {u.x, u.y, u.z, u.w};
    f2 wv = {w, w};
#pragma unroll
    for (int i = 0; i < 4; ++i) {
        h2 xv = bch2(uu[i]);
        f2 xf = {(float)xv[0], (float)xv[1]};
        O[i] += wv * xf;                 // v_pk_fma_f32
    }
}
__device__ __forceinline__ void chunk_accum(
    uint4 f, uint4 c0v, uint4 c1v, uint4 c2v, uint4 c3v,
    const h2* xr, const h2* at, float& S, f2* O)
{
    float p0 = edge_score8(c0v, xr, at);
    float p1 = edge_score8(c1v, xr, at);
    float p2 = edge_score8(c2v, xr, at);
    float p3 = edge_score8(c3v, xr, at);
    p0 += __shfl_xor(p0, 1); p0 += __shfl_xor(p0, 2); p0 += __shfl_xor(p0, 4);
    p1 += __shfl_xor(p1, 1); p1 += __shfl_xor(p1, 2); p1 += __shfl_xor(p1, 4);
    p2 += __shfl_xor(p2, 1); p2 += __shfl_xor(p2, 2); p2 += __shfl_xor(p2, 4);
    p3 += __shfl_xor(p3, 1); p3 += __shfl_xor(p3, 2); p3 += __shfl_xor(p3, 4);
    float w0 = (f.x & 0x80000000u) ? 0.f : __expf(p0);
    float w1 = (f.y & 0x80000000u) ? 0.f : __expf(p1);
    float w2 = (f.z & 0x80000000u) ? 0.f : __expf(p2);
    float w3 = (f.w & 0x80000000u) ? 0.f : __expf(p3);
    S += (w0 + w1) + (w2 + w3);
    accum8v(O, w0, c0v);
    accum8v(O, w1, c1v);
    accum8v(O, w2, c2v);
    accum8v(O, w3, c3v);
}

__global__ __launch_bounds__(256) void bkt_gat_kernel(
    const unsigned* __restrict__ srcsS, const unsigned* __restrict__ dstartAll,
    const __half* __restrict__ xl3, const __half* __restrict__ xr3,
    const float* __restrict__ att0, const float* __restrict__ att1, const float* __restrict__ att2,
    const float* __restrict__ bo0, const float* __restrict__ bo1, const float* __restrict__ bo2,
    __half* __restrict__ h16)
{
    int tag = blockIdx.y, fb = blockIdx.x;
    int cb = fb >> 2;                 // coarse bucket
    int qd = fb & 3;                  // quarter within coarse bucket
    const unsigned* srcs = srcsS + (size_t)tag * NBKT_C * BSTR_S;
    const unsigned* dstart = dstartAll + ((size_t)tag * NBKT_C + cb) * 257 + qd * 64;
    const uint4* xl4 = (const uint4*)xl3 + (size_t)tag * N_NODES * 8;
    const uint4* xr4 = (const uint4*)xr3 + (size_t)tag * N_NODES * 8;
    const float* att = (tag == 0) ? att0 : (tag == 1) ? att1 : att2;
    const float* bo  = (tag == 0) ? bo0  : (tag == 1) ? bo1  : bo2;
    int col0 = tag * 50;

    __shared__ unsigned nextD;
    int tid = threadIdx.x;
    if (tid == 0) nextD = 0;
    __syncthreads();

    // ---- aggregation: 32 groups x 8 lanes; work-stealing over the DPB dsts
    const int l = tid & 7;
    const int grpBase = tid & ~7;
    int c0 = 8 * l;
    h2 at[4];
#pragma unroll
    for (int i = 0; i < 4; ++i) {
        int cc = c0 + 2 * i;
        float lo = (cc < D_OUT) ? att[cc] : 0.f;
        float hi = (cc + 1 < D_OUT) ? att[cc + 1] : 0.f;
        at[i] = h2{(_Float16)lo, (_Float16)hi};
    }
    for (;;) {
        unsigned d;
        if (l == 0) d = atomicAdd(&nextD, 1u);
        d = (unsigned)__shfl((int)d, grpBase);
        if (d >= (unsigned)DPB) break;
        int g = (cb << 8) + (qd << 6) + (int)d;
        if (g >= N_NODES) continue;   // tail guard
        uint4 xru = xr4[g * 8 + l];
        h2 xr[4] = {bch2(xru.x), bch2(xru.y), bch2(xru.z), bch2(xru.w)};
        uint4 xs = xl4[g * 8 + l];

        float q = edge_score8(xs, xr, at);
        q += __shfl_xor(q, 1); q += __shfl_xor(q, 2); q += __shfl_xor(q, 4);
        float S = __expf(q);                    // scores bounded: raw exp safe
        f2 O[4];
#pragma unroll
        for (int i = 0; i < 4; ++i) O[i] = f2{0.f, 0.f};
        accum8v(O, S, xs);

        unsigned j = dstart[d], jE = dstart[d + 1];
        int nch = (int)(jE - j) >> 2;            // chunks of 4 (lists padded x4)
        if (nch > 0) {
            const uint4* s4 = (const uint4*)(srcs + j);   // 16B-aligned (j%4==0)
            uint4 fA, fB, vc, vn;
            uint4 A0, A1, A2, A3, B0, B1, B2, B3;
            fA = s4[0];
            A0 = xl4[(fA.x & 0x7FFFFFFFu) + l];
            A1 = xl4[(fA.y & 0x7FFFFFFFu) + l];
            A2 = xl4[(fA.z & 0x7FFFFFFFu) + l];
            A3 = xl4[(fA.w & 0x7FFFFFFFu) + l];
            if (nch > 1) {
                fB = s4[1];
                B0 = xl4[(fB.x & 0x7FFFFFFFu) + l];
                B1 = xl4[(fB.y & 0x7FFFFFFFu) + l];
                B2 = xl4[(fB.z & 0x7FFFFFFFu) + l];
                B3 = xl4[(fB.w & 0x7FFFFFFFu) + l];
            }
            if (nch > 2) vc = s4[2];
            int k = 0;
            for (;;) {
                // body A: consume chunk k, refill A with chunk k+2
                if (k + 3 < nch) vn = s4[k + 3];
                chunk_accum(fA, A0, A1, A2, A3, xr, at, S, O);
                if (k + 2 < nch) {
                    fA = vc;
                    A0 = xl4[(fA.x & 0x7FFFFFFFu) + l];
                    A1 = xl4[(fA.y & 0x7FFFFFFFu) + l];
                    A2 = xl4[(fA.z & 0x7FFFFFFFu) + l];
                    A3 = xl4[(fA.w & 0x7FFFFFFFu) + l];
                    vc = vn;
                }
                if (++k >= nch) break;
                // body B: consume chunk k, refill B with chunk k+2
                if (k + 3 < nch) vn = s4[k + 3];
                chunk_accum(fB, B0, B1, B2, B3, xr, at, S, O);
                if (k + 2 < nch) {
                    fB = vc;
                    B0 = xl4[(fB.x & 0x7FFFFFFFu) + l];
                    B1 = xl4[(fB.y & 0x7FFFFFFFu) + l];
                    B2 = xl4[(fB.z & 0x7FFFFFFFu) + l];
                    B3 = xl4[(fB.w & 0x7FFFFFFFu) + l];
                    vc = vn;
                }
                if (++k >= nch) break;
            }
        }
        float inv = 1.f / (S + 1e-16f);
        size_t base = (size_t)g * 160 + col0 + c0;
#pragma unroll
        for (int i = 0; i < 4; ++i) {
            int cc = c0 + 2 * i;
            if (cc + 1 < D_OUT) {
                float blo = bo[cc], bhi = bo[cc + 1];
                float vlo = lrelu(O[i][0] * inv + blo, 0.1f);
                float vhi = lrelu(O[i][1] * inv + bhi, 0.1f);
                *(__half2*)&h16[base + 2 * i] = __floats2half2_rn(vlo, vhi);
            }
        }
    }
}

// ---------------- fused MFMA MLP head, wave-independent 16-node tiles ------------
#define HS 168

template<int NOT, int NKS, bool ACT>
__device__ __forceinline__ void head_layer(
    const _Float16* __restrict__ in, _Float16* __restrict__ outp,
    const unsigned short* __restrict__ wp, const float* __restrict__ bias, int l)
{
    const int lm = l & 15, q = l >> 4;
    const _Float16* aBase = in + lm * HS + q * 8;
#pragma unroll
    for (int ot = 0; ot < NOT; ++ot) {
        float4v acc = {0.f, 0.f, 0.f, 0.f};
        const unsigned short* bBase = wp + (ot * NKS) * 512 + l * 8;
#pragma unroll
        for (int ks = 0; ks < NKS; ++ks) {
            half8 a = *(const half8*)(aBase + ks * 32);
            half8 b = *(const half8*)(bBase + ks * 512);
            acc = __builtin_amdgcn_mfma_f32_16x16x32_f16(a, b, acc, 0, 0, 0);
        }
        float bv = bias[ot * 16 + lm];
#pragma unroll
        for (int r = 0; r < 4; ++r) {
            float v = acc[r] + bv;
            if (ACT) v = lrelu(v, 0.1f);
            outp[(q * 4 + r) * HS + ot * 16 + lm] = (_Float16)v;
        }
    }
}

__global__ __launch_bounds__(256) void mfma_head_kernel(
    const __half* __restrict__ h16,
    const unsigned short* __restrict__ wpkAll, const float* __restrict__ biasPad,
    float* __restrict__ out)
{
    __shared__ _Float16 sIn[4][16 * HS];
    __shared__ _Float16 sOut[4][16 * HS];
    int tid = threadIdx.x;
    int w = tid >> 6, l = tid & 63;
    int g0 = blockIdx.x * 64 + w * 16;

    const uint2* hq = (const uint2*)h16;
    for (int idx = l; idx < 16 * 42; idx += 64) {
        int row = idx / 42, qc = idx - row * 42;
        int gn = g0 + row;
        uint2 u = {0u, 0u};
        if (gn < N_NODES && qc < 40) {
            u = hq[(size_t)gn * 40 + qc];
            if (qc == 37) u.y = 0u;
            else if (qc > 37) { u.x = 0u; u.y = 0u; }
        }
        *(uint2*)&sIn[w][row * HS + qc * 4] = u;
    }
    __syncthreads();
    head_layer<10, 5, false>(sIn[w], sOut[w], wpkAll,         biasPad + 0,   l);
    __syncthreads();
    head_layer<6, 5, true >(sOut[w], sIn[w], wpkAll + 25600,  biasPad + 160, l);
    __syncthreads();
    head_layer<2, 3, true >(sIn[w], sOut[w], wpkAll + 40960,  biasPad + 256, l);
    __syncthreads();
    {
        const int lm = l & 15, q = l >> 4;
        float4v acc = {0.f, 0.f, 0.f, 0.f};
        half8 a = *(const half8*)(sOut[w] + lm * HS + q * 8);
        half8 b = *(const half8*)(wpkAll + 44032 + l * 8);
        acc = __builtin_amdgcn_mfma_f32_16x16x32_f16(a, b, acc, 0, 0, 0);
        if (lm < 2) {
            float bv = biasPad[288 + lm];
#pragma unroll
            for (int r = 0; r < 4; ++r) {
                int node = g0 + q * 4 + r;
                if (node < N_NODES) out[node * 2 + lm] = acc[r] + bv;
            }
        }
    }
}

extern "C" void kernel_launch(void* const* d_in, const int* in_sizes, int n_in,
                              void* d_out, int out_size, void* d_ws, size_t ws_size,
                              hipStream_t stream)
{
    const float* x = (const float*)d_in[0];
    const int* eip = (const int*)d_in[1];
    const int* eis = (const int*)d_in[2];
    const int* eiv = (const int*)d_in[3];
    const float *Wl[3], *bl[3], *Wr[3], *br[3], *att[3], *bo[3];
    for (int t = 0; t < 3; ++t) {
        int b = 4 + t * 6;
        Wl[t] = (const float*)d_in[b + 0];
        bl[t] = (const float*)d_in[b + 1];
        Wr[t] = (const float*)d_in[b + 2];
        br[t] = (const float*)d_in[b + 3];
        att[t] = (const float*)d_in[b + 4];
        bo[t] = (const float*)d_in[b + 5];
    }
    const float* projW = (const float*)d_in[22];
    const float* projb = (const float*)d_in[23];
    const float* W1 = (const float*)d_in[24];
    const float* b1 = (const float*)d_in[25];
    const float* W2 = (const float*)d_in[26];
    const float* b2 = (const float*)d_in[27];
    const float* W3 = (const float*)d_in[28];
    const float* b3 = (const float*)d_in[29];
    float* out = (float*)d_out;

    char* ws = (char*)d_ws;
    size_t off = 0;
    auto alloc = [&](size_t bytes) -> char* {
        char* p = ws + off;
        off += (bytes + 255) & ~(size_t)255;
        return p;
    };
    // xl3 has one extra zero row at absolute row index 3*N_NODES (layout compat)
    __half* xl3 = (__half*)alloc(((size_t)3 * N_NODES * 64 + 64) * 2);  // 38.4 MB
    __half* xr3 = (__half*)alloc((size_t)3 * N_NODES * 64 * 2);         // 38.4 MB
    unsigned* bucketedC = (unsigned*)alloc((size_t)3 * NBKT_C * BSTR_C * 4); // 22.5 MB
    unsigned* bcur3 = (unsigned*)alloc((size_t)3 * NBKT_C * 4);
    unsigned* srcsS = (unsigned*)alloc((size_t)3 * NBKT_C * BSTR_S * 4); // 26.1 MB
    unsigned* dstartAll = (unsigned*)alloc((size_t)3 * NBKT_C * 257 * 4); // 1.2 MB
    __half* h16 = (__half*)alloc((size_t)N_NODES * 160 * 2);            // 32 MB
    unsigned short* wpkAll = (unsigned short*)alloc(56832 * 2);
    float* biasPad = (float*)alloc(688 * 4);

    hipMemsetAsync(bcur3, 0, (size_t)3 * NBKT_C * 4, stream);
    pack_all_kernel<<<226, 256, 0, stream>>>(
        projW, W1, W2, W3, projb, b1, b2, b3,
        Wl[0], Wr[0], Wl[1], Wr[1], Wl[2], Wr[2],
        bl[0], br[0], bl[1], br[1], bl[2], br[2],
        wpkAll, biasPad, xl3);

    bkt_scatter_kernel<<<dim3(NBLK_E, 3), 256, 0, stream>>>(eip, eis, eiv, bcur3, bucketedC);

    bkt_sort_kernel<<<dim3(NBKT_C, 3), 256, 0, stream>>>(bucketedC, bcur3, srcsS, dstartAll);

    transform_mfma_kernel<<<(N_NODES + 63) / 64, 256, 0, stream>>>(
        x, wpkAll, biasPad, xl3, xr3);

    bkt_gat_kernel<<<dim3(NBKT_F, 3), 256, 0, stream>>>(
        srcsS, dstartAll, xl3, xr3,
        att[0], att[1], att[2], bo[0], bo[1], bo[2], h16);

    mfma_head_kernel<<<(N_NODES + 63) / 64, 256, 0, stream>>>(h16, wpkAll, biasPad, out);
}

// Round 7
// 399.526 us; speedup vs baseline: 1.0530x; 1.0530x over previous
//
#include <hip/hip_runtime.h>
#include <hip/hip_fp16.h>

#define N_NODES 100000
#define N_EDGES 1600000
#define D_IN 25
#define D_OUT 50
// scatter granularity: coarse buckets of 256 dsts (good write coalescing)
#define NBKT_C 391      // ceil(100000/256)
#define BSTR_C 4800     // mean 4096 + ~11 sigma
#define BSTR_S 5568     // sorted stride: BSTR_C + 256*3 padding (hard bound)
// gat granularity: 64 dsts per block; 4 gat blocks per coarse bucket
#define DPB 64
#define NBKT_F 1563     // ceil(100000/64)
#define EPB 8192        // edges per block in scatter pass
#define NBLK_E 196      // ceil(N_EDGES/EPB)

typedef __attribute__((ext_vector_type(8))) _Float16 half8;
typedef __attribute__((ext_vector_type(2))) _Float16 h2;
typedef __attribute__((ext_vector_type(4))) float float4v;

__device__ __forceinline__ float lrelu(float x, float a) { return fmaxf(x, a * x); }
__device__ __forceinline__ h2 bch2(unsigned u) { return __builtin_bit_cast(h2, u); }

// ---------------- fused bucket scatter: LDS hist -> global reserve -> write ------
__global__ __launch_bounds__(256) void bkt_scatter_kernel(
    const int* __restrict__ eip, const int* __restrict__ eis, const int* __restrict__ eiv,
    unsigned* __restrict__ bcur3, unsigned* __restrict__ bucketedC)
{
    int t = blockIdx.y;
    const int* ei = (t == 0) ? eip : ((t == 1) ? eis : eiv);
    unsigned* bcur = bcur3 + t * NBKT_C;
    unsigned* bucketed = bucketedC + (size_t)t * NBKT_C * BSTR_C;
    __shared__ unsigned h[NBKT_C];
    __shared__ unsigned cur[NBKT_C];
    int tid = threadIdx.x;
    for (int b = tid; b < NBKT_C; b += 256) h[b] = 0;
    __syncthreads();
#pragma unroll
    for (int i = 0; i < EPB / 1024; ++i) {
        int e = blockIdx.x * EPB + (i * 256 + tid) * 4;
        if (e < N_EDGES) {               // N_EDGES % 4 == 0: whole int4 valid
            int4 d4 = *(const int4*)&ei[N_EDGES + e];
            atomicAdd(&h[(unsigned)d4.x >> 8], 1u);
            atomicAdd(&h[(unsigned)d4.y >> 8], 1u);
            atomicAdd(&h[(unsigned)d4.z >> 8], 1u);
            atomicAdd(&h[(unsigned)d4.w >> 8], 1u);
        }
    }
    __syncthreads();
    for (int b = tid; b < NBKT_C; b += 256)
        cur[b] = (unsigned)b * BSTR_C + (h[b] ? atomicAdd(&bcur[b], h[b]) : 0u);
    __syncthreads();
#pragma unroll
    for (int i = 0; i < EPB / 1024; ++i) {
        int e = blockIdx.x * EPB + (i * 256 + tid) * 4;
        if (e < N_EDGES) {
            int4 s4 = *(const int4*)&ei[e];
            int4 d4 = *(const int4*)&ei[N_EDGES + e];
            int ss[4] = {s4.x, s4.y, s4.z, s4.w};
            int dd[4] = {d4.x, d4.y, d4.z, d4.w};
#pragma unroll
            for (int k = 0; k < 4; ++k) {
                unsigned d = (unsigned)dd[k];
                unsigned b = d >> 8;
                unsigned r = atomicAdd(&cur[b], 1u);
                if (r < (b + 1u) * BSTR_C)   // overflow guard (11-sigma margin)
                    bucketed[r] = ((d & 255u) << 17) | (unsigned)ss[k];
            }
        }
    }
}

// ---------------- counting sort: coarse bucket -> per-dst lists + offsets --------
// One block per (coarse bucket, tag). Full 256-dst sort in LDS, per-dst lists
// padded to x4 with flagged dummy zero-row entries, written out coalesced.
// Also emits a within-quarter DESCENDING-DEGREE permutation: gat's 8-lane groups
// steal dsts in that order so concurrently-processed lists have similar length
// (removes the E[max of 8 Poisson]/mean ~ 1.36 lockstep divergence tax).
__global__ __launch_bounds__(256) void bkt_sort_kernel(
    const unsigned* __restrict__ bucketedC, const unsigned* __restrict__ bcur3,
    unsigned* __restrict__ srcsS, unsigned* __restrict__ dstartAll,
    unsigned char* __restrict__ permAll)
{
    int tag = blockIdx.y, cb = blockIdx.x;
    const unsigned* in = bucketedC + ((size_t)tag * NBKT_C + cb) * BSTR_C;
    unsigned* outp = srcsS + (size_t)tag * NBKT_C * BSTR_S + (size_t)cb * BSTR_S;
    unsigned* dstart = dstartAll + ((size_t)tag * NBKT_C + cb) * 257;
    unsigned char* perm = permAll + (((size_t)tag * NBKT_C + cb) << 8);
    __shared__ unsigned hist[256];
    __shared__ unsigned cnt2[256];
    __shared__ unsigned cur[256];
    __shared__ __align__(16) unsigned sbuf[BSTR_S];
    __shared__ unsigned totS;
    int tid = threadIdx.x;
    unsigned cnt = bcur3[tag * NBKT_C + cb];
    if (cnt > BSTR_C) cnt = BSTR_C;
    hist[tid] = 0;
    __syncthreads();
    for (unsigned i = tid; i < cnt; i += 256) atomicAdd(&hist[in[i] >> 17], 1u);
    __syncthreads();
    unsigned c = hist[tid];
    cnt2[tid] = c;
    unsigned pc = (c + 3u) & ~3u;        // pad each dst's list to multiple of 4
    hist[tid] = pc;
    __syncthreads();
    for (int off = 1; off < 256; off <<= 1) {   // inclusive scan of padded counts
        unsigned v = (tid >= off) ? hist[tid - off] : 0u;
        __syncthreads();
        hist[tid] += v;
        __syncthreads();
    }
    unsigned excl = hist[tid] - pc;
    cur[tid] = excl;
    dstart[tid] = (unsigned)cb * BSTR_S + excl;   // absolute within-tag offset
    if (tid == 255) { dstart[256] = (unsigned)cb * BSTR_S + hist[255]; totS = hist[255]; }
    {   // within-quarter descending-degree rank (ties broken by index) -> perm
        int q0 = tid & ~63;
        int rank = 0;
        for (int j = 0; j < 64; ++j) {
            unsigned cj = cnt2[q0 + j];
            rank += (cj > c) || (cj == c && (q0 + j) < tid);
        }
        perm[q0 + rank] = (unsigned char)(tid & 63);
    }
    __syncthreads();
    for (unsigned i = tid; i < cnt; i += 256) {   // scatter into LDS sorted order
        unsigned w = in[i];
        unsigned r = atomicAdd(&cur[w >> 17], 1u);
        sbuf[r] = (w & 0x1FFFFu) << 3;            // pre-scaled uint4 row index
    }
    {
        const unsigned DUMMY = 0x80000000u | ((unsigned)(3 * N_NODES) << 3);
        for (unsigned k = c; k < pc; ++k) sbuf[excl + k] = DUMMY;  // disjoint slots
    }
    __syncthreads();
    unsigned tot = totS;                 // <= BSTR_S by construction
    for (unsigned i = tid; i < tot; i += 256) outp[i] = sbuf[i];
}

// ---------------- pack: head B-fragments (fp16) + transform weights + biases -----
// wpkAll: [0:25600) proj  [25600:40960) cls1  [40960:44032) cls2  [44032:44544) cls3
//         [44544:56832) transform 6 mats x 4 chunks x 512
// biasPad: [0:304) head; [304:688) transform 6 x 64
__device__ __forceinline__ void pack_seg(
    const float* __restrict__ W, unsigned short* __restrict__ outp,
    int K, int O, int NKS, int idx)
{
    int f = idx >> 9, r = idx & 511;
    int l = r >> 3, j = r & 7;
    int ot = f / NKS, ks = f - ot * NKS;
    int k = ks * 32 + (l >> 4) * 8 + j;
    int o = ot * 16 + (l & 15);
    float val = (k < K && o < O) ? W[k * O + o] : 0.f;
    outp[idx] = __half_as_ushort(__float2half_rn(val));
}

__global__ __launch_bounds__(256) void pack_all_kernel(
    const float* __restrict__ projW, const float* __restrict__ W1,
    const float* __restrict__ W2, const float* __restrict__ W3,
    const float* __restrict__ b0, const float* __restrict__ b1,
    const float* __restrict__ b2, const float* __restrict__ b3,
    const float* __restrict__ Wl0, const float* __restrict__ Wr0,
    const float* __restrict__ Wl1, const float* __restrict__ Wr1,
    const float* __restrict__ Wl2, const float* __restrict__ Wr2,
    const float* __restrict__ bl0, const float* __restrict__ br0,
    const float* __restrict__ bl1, const float* __restrict__ br1,
    const float* __restrict__ bl2, const float* __restrict__ br2,
    unsigned short* __restrict__ wpkAll, float* __restrict__ biasPad,
    __half* __restrict__ xl3)
{
    int gid = blockIdx.x * 256 + threadIdx.x;
    if (gid < 25600) pack_seg(projW, wpkAll, 150, 150, 5, gid);
    else if (gid < 40960) pack_seg(W1, wpkAll + 25600, 150, 75, 5, gid - 25600);
    else if (gid < 44032) pack_seg(W2, wpkAll + 40960, 75, 30, 3, gid - 40960);
    else if (gid < 44544) pack_seg(W3, wpkAll + 44032, 30, 2, 1, gid - 44032);
    else if (gid < 56832) {
        int t = gid - 44544;
        int mat = t >> 11, idx = t & 2047;
        const float* Wm = (mat == 0) ? Wl0 : (mat == 1) ? Wr0 : (mat == 2) ? Wl1
                        : (mat == 3) ? Wr1 : (mat == 4) ? Wl2 : Wr2;
        int ot = idx >> 9, r = idx & 511;
        int l = r >> 3, j = r & 7;
        int k = (l >> 4) * 8 + j;
        int o = ot * 16 + (l & 15);
        float val = (k < D_IN && o < D_OUT) ? Wm[k * D_OUT + o] : 0.f;
        wpkAll[44544 + t] = __half_as_ushort(__float2half_rn(val));
    } else if (gid < 57520) {
        int t = gid - 56832;
        float v;
        if (t < 304) {
            if (t < 160) v = (t < 150) ? b0[t] : 0.f;
            else if (t < 256) { int i = t - 160; v = (i < 75) ? b1[i] : 0.f; }
            else if (t < 288) { int i = t - 256; v = (i < 30) ? b2[i] : 0.f; }
            else { int i = t - 288; v = (i < 2) ? b3[i] : 0.f; }
        } else {
            int ii = t - 304;
            int mat = ii >> 6, o = ii & 63;
            const float* bm = (mat == 0) ? bl0 : (mat == 1) ? br0 : (mat == 2) ? bl1
                            : (mat == 3) ? br1 : (mat == 4) ? bl2 : br2;
            v = (o < D_OUT) ? bm[o] : 0.f;
        }
        biasPad[t] = v;
    } else if (gid < 57584) {
        // zero row at absolute row 3*N_NODES: dummy-edge gather target
        xl3[(size_t)3 * N_NODES * 64 + (gid - 57520)] = __ushort_as_half((unsigned short)0);
    }
}

// ---------------- MFMA node transform: xl/xr (6 mats) via 16x16x32 f16 -----------
#define TSTR 32
#define OSTR 72

__global__ __launch_bounds__(256) void transform_mfma_kernel(
    const float* __restrict__ x,
    const unsigned short* __restrict__ wpkAll, const float* __restrict__ biasPad,
    __half* __restrict__ xl3, __half* __restrict__ xr3)
{
    __shared__ _Float16 sX[64 * TSTR];
    __shared__ _Float16 sO[4][16 * OSTR];
    int tid = threadIdx.x;
    int w = tid >> 6, l = tid & 63;
    int g0 = blockIdx.x * 64;
    for (int i = tid; i < 64 * D_IN; i += 256) {
        int r = i / D_IN, c = i - r * D_IN;
        int gr = g0 + r;
        sX[r * TSTR + c] = (gr < N_NODES) ? (_Float16)x[(size_t)gr * D_IN + c] : (_Float16)0.f;
    }
    for (int i = tid; i < 64 * 7; i += 256) {
        int r = i / 7, c = D_IN + (i - r * 7);
        sX[r * TSTR + c] = (_Float16)0.f;
    }
    __syncthreads();
    int lm = l & 15, q = l >> 4;
    half8 a = *(const half8*)(sX + (w * 16 + lm) * TSTR + q * 8);
    const unsigned short* wT = wpkAll + 44544;
#pragma unroll
    for (int mat = 0; mat < 6; ++mat) {
        float4v acc[4];
#pragma unroll
        for (int ot = 0; ot < 4; ++ot) {
            half8 b = *(const half8*)(wT + (mat * 4 + ot) * 512 + l * 8);
            float4v z = {0.f, 0.f, 0.f, 0.f};
            acc[ot] = __builtin_amdgcn_mfma_f32_16x16x32_f16(a, b, z, 0, 0, 0);
        }
#pragma unroll
        for (int ot = 0; ot < 4; ++ot) {
            float bv = biasPad[304 + mat * 64 + ot * 16 + lm];
#pragma unroll
            for (int r = 0; r < 4; ++r)
                sO[w][(q * 4 + r) * OSTR + ot * 16 + lm] = (_Float16)(acc[ot][r] + bv);
        }
        __half* dst = ((mat & 1) ? xr3 : xl3) + (size_t)(mat >> 1) * N_NODES * 64;
#pragma unroll
        for (int it = 0; it < 2; ++it) {
            int idx = it * 64 + l;
            int rr = idx >> 3, cc = idx & 7;
            int gr = g0 + w * 16 + rr;
            if (gr < N_NODES) {
                uint4 v = *(const uint4*)&sO[w][rr * OSTR + cc * 8];
                *(uint4*)&dst[(size_t)gr * 64 + cc * 8] = v;
            }
        }
    }
}

// ---------------- GATv2 aggregation over pre-sorted lists ------------------------
// One block per (64-dst group, tag). Round-5 inner loop (44 VGPR — MUST stay
// <=64: crossing 64 halves the wave ceiling, round-6 measured 72 VGPR -> 29%
// occupancy, 145us). Dsts are stolen in descending-degree order via permL so
// the 8 lockstep groups of each wave have near-equal list lengths.
__device__ __forceinline__ float edge_score8(uint4 u, const h2* xr, const h2* at)
{
    const h2 k2 = {(_Float16)0.2f, (_Float16)0.2f};
    float acc = 0.f;
    unsigned uu[4] = {u.x, u.y, u.z, u.w};
#pragma unroll
    for (int i = 0; i < 4; ++i) {
        h2 m = bch2(uu[i]) + xr[i];
        m = __builtin_elementwise_max(m, m * k2);
        acc = __builtin_amdgcn_fdot2(m, at[i], acc, false);
    }
    return acc;
}
__device__ __forceinline__ void accum8(float2* O, float w, uint4 u)
{
    unsigned uu[4] = {u.x, u.y, u.z, u.w};
#pragma unroll
    for (int i = 0; i < 4; ++i) {
        h2 xv = bch2(uu[i]);
        O[i].x += w * (float)xv[0];
        O[i].y += w * (float)xv[1];
    }
}

__global__ __launch_bounds__(256) void bkt_gat_kernel(
    const unsigned* __restrict__ srcsS, const unsigned* __restrict__ dstartAll,
    const unsigned char* __restrict__ permAll,
    const __half* __restrict__ xl3, const __half* __restrict__ xr3,
    const float* __restrict__ att0, const float* __restrict__ att1, const float* __restrict__ att2,
    const float* __restrict__ bo0, const float* __restrict__ bo1, const float* __restrict__ bo2,
    __half* __restrict__ h16)
{
    int tag = blockIdx.y, fb = blockIdx.x;
    int cb = fb >> 2;                 // coarse bucket
    int qd = fb & 3;                  // quarter within coarse bucket
    const unsigned* srcs = srcsS + (size_t)tag * NBKT_C * BSTR_S;
    const unsigned* dstart = dstartAll + ((size_t)tag * NBKT_C + cb) * 257 + qd * 64;
    const uint4* xl4 = (const uint4*)xl3 + (size_t)tag * N_NODES * 8;
    const uint4* xr4 = (const uint4*)xr3 + (size_t)tag * N_NODES * 8;
    const float* att = (tag == 0) ? att0 : (tag == 1) ? att1 : att2;
    const float* bo  = (tag == 0) ? bo0  : (tag == 1) ? bo1  : bo2;
    int col0 = tag * 50;

    __shared__ unsigned nextD;
    __shared__ unsigned char permL[DPB];
    int tid = threadIdx.x;
    if (tid < DPB)
        permL[tid] = permAll[(((size_t)tag * NBKT_C + cb) << 8) + (qd << 6) + tid];
    if (tid == 0) nextD = 0;
    __syncthreads();

    // ---- aggregation: 32 groups x 8 lanes; work-stealing over the DPB dsts
    const int l = tid & 7;
    const int grpBase = tid & ~7;
    int c0 = 8 * l;
    h2 at[4];
#pragma unroll
    for (int i = 0; i < 4; ++i) {
        int cc = c0 + 2 * i;
        float lo = (cc < D_OUT) ? att[cc] : 0.f;
        float hi = (cc + 1 < D_OUT) ? att[cc + 1] : 0.f;
        at[i] = h2{(_Float16)lo, (_Float16)hi};
    }
    for (;;) {
        unsigned d;
        if (l == 0) d = atomicAdd(&nextD, 1u);
        d = (unsigned)__shfl((int)d, grpBase);
        if (d >= (unsigned)DPB) break;
        int pd = (int)permL[d];       // degree-sorted steal order
        int g = (cb << 8) + (qd << 6) + pd;
        if (g >= N_NODES) continue;   // tail guard
        uint4 xru = xr4[g * 8 + l];
        h2 xr[4] = {bch2(xru.x), bch2(xru.y), bch2(xru.z), bch2(xru.w)};
        uint4 xs = xl4[g * 8 + l];

        float q = edge_score8(xs, xr, at);
        q += __shfl_xor(q, 1); q += __shfl_xor(q, 2); q += __shfl_xor(q, 4);
        float S = __expf(q);                    // scores bounded: raw exp safe
        float2 O[4] = {{0.f, 0.f}, {0.f, 0.f}, {0.f, 0.f}, {0.f, 0.f}};
        accum8(O, S, xs);

        unsigned j = dstart[pd], jE = dstart[pd + 1];
        if (j < jE) {
            uint4 vv = *(const uint4*)&srcs[j];        // 16B-aligned (j % 4 == 0)
            uint4 c0v = xl4[(vv.x & 0x7FFFFFFFu) + l];
            uint4 c1v = xl4[(vv.y & 0x7FFFFFFFu) + l];
            uint4 c2v = xl4[(vv.z & 0x7FFFFFFFu) + l];
            uint4 c3v = xl4[(vv.w & 0x7FFFFFFFu) + l];
            for (;;) {
                j += 4;
                bool more = j < jE;
                uint4 nv, p0v, p1v, p2v, p3v;
                if (more) {
                    nv = *(const uint4*)&srcs[j];
                    p0v = xl4[(nv.x & 0x7FFFFFFFu) + l];
                    p1v = xl4[(nv.y & 0x7FFFFFFFu) + l];
                    p2v = xl4[(nv.z & 0x7FFFFFFFu) + l];
                    p3v = xl4[(nv.w & 0x7FFFFFFFu) + l];
                }
                float p0 = edge_score8(c0v, xr, at);
                float p1 = edge_score8(c1v, xr, at);
                float p2 = edge_score8(c2v, xr, at);
                float p3 = edge_score8(c3v, xr, at);
                p0 += __shfl_xor(p0, 1); p0 += __shfl_xor(p0, 2); p0 += __shfl_xor(p0, 4);
                p1 += __shfl_xor(p1, 1); p1 += __shfl_xor(p1, 2); p1 += __shfl_xor(p1, 4);
                p2 += __shfl_xor(p2, 1); p2 += __shfl_xor(p2, 2); p2 += __shfl_xor(p2, 4);
                p3 += __shfl_xor(p3, 1); p3 += __shfl_xor(p3, 2); p3 += __shfl_xor(p3, 4);
                float w0 = (vv.x & 0x80000000u) ? 0.f : __expf(p0);
                float w1 = (vv.y & 0x80000000u) ? 0.f : __expf(p1);
                float w2 = (vv.z & 0x80000000u) ? 0.f : __expf(p2);
                float w3 = (vv.w & 0x80000000u) ? 0.f : __expf(p3);
                S += (w0 + w1) + (w2 + w3);
                accum8(O, w0, c0v);
                accum8(O, w1, c1v);
                accum8(O, w2, c2v);
                accum8(O, w3, c3v);
                if (!more) break;
                vv = nv; c0v = p0v; c1v = p1v; c2v = p2v; c3v = p3v;
            }
        }
        float inv = 1.f / (S + 1e-16f);
        size_t base = (size_t)g * 160 + col0 + c0;
#pragma unroll
        for (int i = 0; i < 4; ++i) {
            int cc = c0 + 2 * i;
            if (cc + 1 < D_OUT) {
                float blo = bo[cc], bhi = bo[cc + 1];
                float vlo = lrelu(O[i].x * inv + blo, 0.1f);
                float vhi = lrelu(O[i].y * inv + bhi, 0.1f);
                *(__half2*)&h16[base + 2 * i] = __floats2half2_rn(vlo, vhi);
            }
        }
    }
}

// ---------------- fused MFMA MLP head, wave-independent 16-node tiles ------------
#define HS 168

template<int NOT, int NKS, bool ACT>
__device__ __forceinline__ void head_layer(
    const _Float16* __restrict__ in, _Float16* __restrict__ outp,
    const unsigned short* __restrict__ wp, const float* __restrict__ bias, int l)
{
    const int lm = l & 15, q = l >> 4;
    const _Float16* aBase = in + lm * HS + q * 8;
#pragma unroll
    for (int ot = 0; ot < NOT; ++ot) {
        float4v acc = {0.f, 0.f, 0.f, 0.f};
        const unsigned short* bBase = wp + (ot * NKS) * 512 + l * 8;
#pragma unroll
        for (int ks = 0; ks < NKS; ++ks) {
            half8 a = *(const half8*)(aBase + ks * 32);
            half8 b = *(const half8*)(bBase + ks * 512);
            acc = __builtin_amdgcn_mfma_f32_16x16x32_f16(a, b, acc, 0, 0, 0);
        }
        float bv = bias[ot * 16 + lm];
#pragma unroll
        for (int r = 0; r < 4; ++r) {
            float v = acc[r] + bv;
            if (ACT) v = lrelu(v, 0.1f);
            outp[(q * 4 + r) * HS + ot * 16 + lm] = (_Float16)v;
        }
    }
}

__global__ __launch_bounds__(256) void mfma_head_kernel(
    const __half* __restrict__ h16,
    const unsigned short* __restrict__ wpkAll, const float* __restrict__ biasPad,
    float* __restrict__ out)
{
    __shared__ _Float16 sIn[4][16 * HS];
    __shared__ _Float16 sOut[4][16 * HS];
    int tid = threadIdx.x;
    int w = tid >> 6, l = tid & 63;
    int g0 = blockIdx.x * 64 + w * 16;

    const uint2* hq = (const uint2*)h16;
    for (int idx = l; idx < 16 * 42; idx += 64) {
        int row = idx / 42, qc = idx - row * 42;
        int gn = g0 + row;
        uint2 u = {0u, 0u};
        if (gn < N_NODES && qc < 40) {
            u = hq[(size_t)gn * 40 + qc];
            if (qc == 37) u.y = 0u;
            else if (qc > 37) { u.x = 0u; u.y = 0u; }
        }
        *(uint2*)&sIn[w][row * HS + qc * 4] = u;
    }
    __syncthreads();
    head_layer<10, 5, false>(sIn[w], sOut[w], wpkAll,         biasPad + 0,   l);
    __syncthreads();
    head_layer<6, 5, true >(sOut[w], sIn[w], wpkAll + 25600,  biasPad + 160, l);
    __syncthreads();
    head_layer<2, 3, true >(sIn[w], sOut[w], wpkAll + 40960,  biasPad + 256, l);
    __syncthreads();
    {
        const int lm = l & 15, q = l >> 4;
        float4v acc = {0.f, 0.f, 0.f, 0.f};
        half8 a = *(const half8*)(sOut[w] + lm * HS + q * 8);
        half8 b = *(const half8*)(wpkAll + 44032 + l * 8);
        acc = __builtin_amdgcn_mfma_f32_16x16x32_f16(a, b, acc, 0, 0, 0);
        if (lm < 2) {
            float bv = biasPad[288 + lm];
#pragma unroll
            for (int r = 0; r < 4; ++r) {
                int node = g0 + q * 4 + r;
                if (node < N_NODES) out[node * 2 + lm] = acc[r] + bv;
            }
        }
    }
}

extern "C" void kernel_launch(void* const* d_in, const int* in_sizes, int n_in,
                              void* d_out, int out_size, void* d_ws, size_t ws_size,
                              hipStream_t stream)
{
    const float* x = (const float*)d_in[0];
    const int* eip = (const int*)d_in[1];
    const int* eis = (const int*)d_in[2];
    const int* eiv = (const int*)d_in[3];
    const float *Wl[3], *bl[3], *Wr[3], *br[3], *att[3], *bo[3];
    for (int t = 0; t < 3; ++t) {
        int b = 4 + t * 6;
        Wl[t] = (const float*)d_in[b + 0];
        bl[t] = (const float*)d_in[b + 1];
        Wr[t] = (const float*)d_in[b + 2];
        br[t] = (const float*)d_in[b + 3];
        att[t] = (const float*)d_in[b + 4];
        bo[t] = (const float*)d_in[b + 5];
    }
    const float* projW = (const float*)d_in[22];
    const float* projb = (const float*)d_in[23];
    const float* W1 = (const float*)d_in[24];
    const float* b1 = (const float*)d_in[25];
    const float* W2 = (const float*)d_in[26];
    const float* b2 = (const float*)d_in[27];
    const float* W3 = (const float*)d_in[28];
    const float* b3 = (const float*)d_in[29];
    float* out = (float*)d_out;

    char* ws = (char*)d_ws;
    size_t off = 0;
    auto alloc = [&](size_t bytes) -> char* {
        char* p = ws + off;
        off += (bytes + 255) & ~(size_t)255;
        return p;
    };
    // xl3 has one extra zero row at absolute row index 3*N_NODES (dummy target)
    __half* xl3 = (__half*)alloc(((size_t)3 * N_NODES * 64 + 64) * 2);  // 38.4 MB
    __half* xr3 = (__half*)alloc((size_t)3 * N_NODES * 64 * 2);         // 38.4 MB
    unsigned* bucketedC = (unsigned*)alloc((size_t)3 * NBKT_C * BSTR_C * 4); // 22.5 MB
    unsigned* bcur3 = (unsigned*)alloc((size_t)3 * NBKT_C * 4);
    unsigned* srcsS = (unsigned*)alloc((size_t)3 * NBKT_C * BSTR_S * 4); // 26.1 MB
    unsigned* dstartAll = (unsigned*)alloc((size_t)3 * NBKT_C * 257 * 4); // 1.2 MB
    unsigned char* permAll = (unsigned char*)alloc((size_t)3 * NBKT_C * 256); // 0.3 MB
    __half* h16 = (__half*)alloc((size_t)N_NODES * 160 * 2);            // 32 MB
    unsigned short* wpkAll = (unsigned short*)alloc(56832 * 2);
    float* biasPad = (float*)alloc(688 * 4);

    hipMemsetAsync(bcur3, 0, (size_t)3 * NBKT_C * 4, stream);
    pack_all_kernel<<<226, 256, 0, stream>>>(
        projW, W1, W2, W3, projb, b1, b2, b3,
        Wl[0], Wr[0], Wl[1], Wr[1], Wl[2], Wr[2],
        bl[0], br[0], bl[1], br[1], bl[2], br[2],
        wpkAll, biasPad, xl3);

    bkt_scatter_kernel<<<dim3(NBLK_E, 3), 256, 0, stream>>>(eip, eis, eiv, bcur3, bucketedC);

    bkt_sort_kernel<<<dim3(NBKT_C, 3), 256, 0, stream>>>(bucketedC, bcur3, srcsS, dstartAll, permAll);

    transform_mfma_kernel<<<(N_NODES + 63) / 64, 256, 0, stream>>>(
        x, wpkAll, biasPad, xl3, xr3);

    bkt_gat_kernel<<<dim3(NBKT_F, 3), 256, 0, stream>>>(
        srcsS, dstartAll, permAll, xl3, xr3,
        att[0], att[1], att[2], bo[0], bo[1], bo[2], h16);

    mfma_head_kernel<<<(N_NODES + 63) / 64, 256, 0, stream>>>(h16, wpkAll, biasPad, out);
}

// Round 8
// 389.865 us; speedup vs baseline: 1.0791x; 1.0248x over previous
//
#include <hip/hip_runtime.h>
#include <hip/hip_fp16.h>

#define N_NODES 100000
#define N_EDGES 1600000
#define D_IN 25
#define D_OUT 50
// scatter granularity: coarse buckets of 256 dsts (good write coalescing)
#define NBKT_C 391      // ceil(100000/256)
#define BSTR_C 4800     // mean 4096 + ~11 sigma
#define BSTR_S 5568     // sorted stride: BSTR_C + 256*3 padding (hard bound)
// gat granularity: 64 dsts per block; 4 gat blocks per coarse bucket
#define DPB 64
#define NBKT_F 1563     // ceil(100000/64)
#define EPB 8192        // edges per block in scatter pass
#define NBLK_E 196      // ceil(N_EDGES/EPB)

typedef __attribute__((ext_vector_type(8))) _Float16 half8;
typedef __attribute__((ext_vector_type(2))) _Float16 h2;
typedef __attribute__((ext_vector_type(4))) float float4v;
typedef __attribute__((ext_vector_type(2))) float f2;

__device__ __forceinline__ float lrelu(float x, float a) { return fmaxf(x, a * x); }
__device__ __forceinline__ h2 bch2(unsigned u) { return __builtin_bit_cast(h2, u); }

// ---------------- fused bucket scatter: LDS hist -> global reserve -> write ------
__global__ __launch_bounds__(256) void bkt_scatter_kernel(
    const int* __restrict__ eip, const int* __restrict__ eis, const int* __restrict__ eiv,
    unsigned* __restrict__ bcur3, unsigned* __restrict__ bucketedC)
{
    int t = blockIdx.y;
    const int* ei = (t == 0) ? eip : ((t == 1) ? eis : eiv);
    unsigned* bcur = bcur3 + t * NBKT_C;
    unsigned* bucketed = bucketedC + (size_t)t * NBKT_C * BSTR_C;
    __shared__ unsigned h[NBKT_C];
    __shared__ unsigned cur[NBKT_C];
    int tid = threadIdx.x;
    for (int b = tid; b < NBKT_C; b += 256) h[b] = 0;
    __syncthreads();
#pragma unroll
    for (int i = 0; i < EPB / 1024; ++i) {
        int e = blockIdx.x * EPB + (i * 256 + tid) * 4;
        if (e < N_EDGES) {               // N_EDGES % 4 == 0: whole int4 valid
            int4 d4 = *(const int4*)&ei[N_EDGES + e];
            atomicAdd(&h[(unsigned)d4.x >> 8], 1u);
            atomicAdd(&h[(unsigned)d4.y >> 8], 1u);
            atomicAdd(&h[(unsigned)d4.z >> 8], 1u);
            atomicAdd(&h[(unsigned)d4.w >> 8], 1u);
        }
    }
    __syncthreads();
    for (int b = tid; b < NBKT_C; b += 256)
        cur[b] = (unsigned)b * BSTR_C + (h[b] ? atomicAdd(&bcur[b], h[b]) : 0u);
    __syncthreads();
#pragma unroll
    for (int i = 0; i < EPB / 1024; ++i) {
        int e = blockIdx.x * EPB + (i * 256 + tid) * 4;
        if (e < N_EDGES) {
            int4 s4 = *(const int4*)&ei[e];
            int4 d4 = *(const int4*)&ei[N_EDGES + e];
            int ss[4] = {s4.x, s4.y, s4.z, s4.w};
            int dd[4] = {d4.x, d4.y, d4.z, d4.w};
#pragma unroll
            for (int k = 0; k < 4; ++k) {
                unsigned d = (unsigned)dd[k];
                unsigned b = d >> 8;
                unsigned r = atomicAdd(&cur[b], 1u);
                if (r < (b + 1u) * BSTR_C)   // overflow guard (11-sigma margin)
                    bucketed[r] = ((d & 255u) << 17) | (unsigned)ss[k];
            }
        }
    }
}

// ---------------- counting sort: coarse bucket -> per-dst lists + offsets --------
// One block per (coarse bucket, tag). Full 256-dst sort in LDS, per-dst lists
// padded to x4 with flagged dummy zero-row entries, written out coalesced.
// Also emits a within-quarter DESCENDING-DEGREE permutation: gat's 8-lane groups
// steal dsts in that order so concurrently-processed lists have similar length.
__global__ __launch_bounds__(256) void bkt_sort_kernel(
    const unsigned* __restrict__ bucketedC, const unsigned* __restrict__ bcur3,
    unsigned* __restrict__ srcsS, unsigned* __restrict__ dstartAll,
    unsigned char* __restrict__ permAll)
{
    int tag = blockIdx.y, cb = blockIdx.x;
    const unsigned* in = bucketedC + ((size_t)tag * NBKT_C + cb) * BSTR_C;
    unsigned* outp = srcsS + (size_t)tag * NBKT_C * BSTR_S + (size_t)cb * BSTR_S;
    unsigned* dstart = dstartAll + ((size_t)tag * NBKT_C + cb) * 257;
    unsigned char* perm = permAll + (((size_t)tag * NBKT_C + cb) << 8);
    __shared__ unsigned hist[256];
    __shared__ unsigned cnt2[256];
    __shared__ unsigned cur[256];
    __shared__ __align__(16) unsigned sbuf[BSTR_S];
    __shared__ unsigned totS;
    int tid = threadIdx.x;
    unsigned cnt = bcur3[tag * NBKT_C + cb];
    if (cnt > BSTR_C) cnt = BSTR_C;
    hist[tid] = 0;
    __syncthreads();
    for (unsigned i = tid; i < cnt; i += 256) atomicAdd(&hist[in[i] >> 17], 1u);
    __syncthreads();
    unsigned c = hist[tid];
    cnt2[tid] = c;
    unsigned pc = (c + 3u) & ~3u;        // pad each dst's list to multiple of 4
    hist[tid] = pc;
    __syncthreads();
    for (int off = 1; off < 256; off <<= 1) {   // inclusive scan of padded counts
        unsigned v = (tid >= off) ? hist[tid - off] : 0u;
        __syncthreads();
        hist[tid] += v;
        __syncthreads();
    }
    unsigned excl = hist[tid] - pc;
    cur[tid] = excl;
    dstart[tid] = (unsigned)cb * BSTR_S + excl;   // absolute within-tag offset
    if (tid == 255) { dstart[256] = (unsigned)cb * BSTR_S + hist[255]; totS = hist[255]; }
    {   // within-quarter descending-degree rank (ties broken by index) -> perm
        int q0 = tid & ~63;
        int rank = 0;
        for (int j = 0; j < 64; ++j) {
            unsigned cj = cnt2[q0 + j];
            rank += (cj > c) || (cj == c && (q0 + j) < tid);
        }
        perm[q0 + rank] = (unsigned char)(tid & 63);
    }
    __syncthreads();
    for (unsigned i = tid; i < cnt; i += 256) {   // scatter into LDS sorted order
        unsigned w = in[i];
        unsigned r = atomicAdd(&cur[w >> 17], 1u);
        sbuf[r] = (w & 0x1FFFFu) << 3;            // pre-scaled uint4 row index
    }
    {
        const unsigned DUMMY = 0x80000000u | ((unsigned)(3 * N_NODES) << 3);
        for (unsigned k = c; k < pc; ++k) sbuf[excl + k] = DUMMY;  // disjoint slots
    }
    __syncthreads();
    unsigned tot = totS;                 // <= BSTR_S by construction
    for (unsigned i = tid; i < tot; i += 256) outp[i] = sbuf[i];
}

// ---------------- pack: head B-fragments (fp16) + transform weights + biases -----
__device__ __forceinline__ void pack_seg(
    const float* __restrict__ W, unsigned short* __restrict__ outp,
    int K, int O, int NKS, int idx)
{
    int f = idx >> 9, r = idx & 511;
    int l = r >> 3, j = r & 7;
    int ot = f / NKS, ks = f - ot * NKS;
    int k = ks * 32 + (l >> 4) * 8 + j;
    int o = ot * 16 + (l & 15);
    float val = (k < K && o < O) ? W[k * O + o] : 0.f;
    outp[idx] = __half_as_ushort(__float2half_rn(val));
}

__global__ __launch_bounds__(256) void pack_all_kernel(
    const float* __restrict__ projW, const float* __restrict__ W1,
    const float* __restrict__ W2, const float* __restrict__ W3,
    const float* __restrict__ b0, const float* __restrict__ b1,
    const float* __restrict__ b2, const float* __restrict__ b3,
    const float* __restrict__ Wl0, const float* __restrict__ Wr0,
    const float* __restrict__ Wl1, const float* __restrict__ Wr1,
    const float* __restrict__ Wl2, const float* __restrict__ Wr2,
    const float* __restrict__ bl0, const float* __restrict__ br0,
    const float* __restrict__ bl1, const float* __restrict__ br1,
    const float* __restrict__ bl2, const float* __restrict__ br2,
    unsigned short* __restrict__ wpkAll, float* __restrict__ biasPad,
    __half* __restrict__ xl3)
{
    int gid = blockIdx.x * 256 + threadIdx.x;
    if (gid < 25600) pack_seg(projW, wpkAll, 150, 150, 5, gid);
    else if (gid < 40960) pack_seg(W1, wpkAll + 25600, 150, 75, 5, gid - 25600);
    else if (gid < 44032) pack_seg(W2, wpkAll + 40960, 75, 30, 3, gid - 40960);
    else if (gid < 44544) pack_seg(W3, wpkAll + 44032, 30, 2, 1, gid - 44032);
    else if (gid < 56832) {
        int t = gid - 44544;
        int mat = t >> 11, idx = t & 2047;
        const float* Wm = (mat == 0) ? Wl0 : (mat == 1) ? Wr0 : (mat == 2) ? Wl1
                        : (mat == 3) ? Wr1 : (mat == 4) ? Wl2 : Wr2;
        int ot = idx >> 9, r = idx & 511;
        int l = r >> 3, j = r & 7;
        int k = (l >> 4) * 8 + j;
        int o = ot * 16 + (l & 15);
        float val = (k < D_IN && o < D_OUT) ? Wm[k * D_OUT + o] : 0.f;
        wpkAll[44544 + t] = __half_as_ushort(__float2half_rn(val));
    } else if (gid < 57520) {
        int t = gid - 56832;
        float v;
        if (t < 304) {
            if (t < 160) v = (t < 150) ? b0[t] : 0.f;
            else if (t < 256) { int i = t - 160; v = (i < 75) ? b1[i] : 0.f; }
            else if (t < 288) { int i = t - 256; v = (i < 30) ? b2[i] : 0.f; }
            else { int i = t - 288; v = (i < 2) ? b3[i] : 0.f; }
        } else {
            int ii = t - 304;
            int mat = ii >> 6, o = ii & 63;
            const float* bm = (mat == 0) ? bl0 : (mat == 1) ? br0 : (mat == 2) ? bl1
                            : (mat == 3) ? br1 : (mat == 4) ? bl2 : br2;
            v = (o < D_OUT) ? bm[o] : 0.f;
        }
        biasPad[t] = v;
    } else if (gid < 57584) {
        // zero row at absolute row 3*N_NODES: dummy-edge gather target
        xl3[(size_t)3 * N_NODES * 64 + (gid - 57520)] = __ushort_as_half((unsigned short)0);
    }
}

// ---------------- MFMA node transform: xl/xr (6 mats) via 16x16x32 f16 -----------
#define TSTR 32
#define OSTR 72

__global__ __launch_bounds__(256) void transform_mfma_kernel(
    const float* __restrict__ x,
    const unsigned short* __restrict__ wpkAll, const float* __restrict__ biasPad,
    __half* __restrict__ xl3, __half* __restrict__ xr3)
{
    __shared__ _Float16 sX[64 * TSTR];
    __shared__ _Float16 sO[4][16 * OSTR];
    int tid = threadIdx.x;
    int w = tid >> 6, l = tid & 63;
    int g0 = blockIdx.x * 64;
    for (int i = tid; i < 64 * D_IN; i += 256) {
        int r = i / D_IN, c = i - r * D_IN;
        int gr = g0 + r;
        sX[r * TSTR + c] = (gr < N_NODES) ? (_Float16)x[(size_t)gr * D_IN + c] : (_Float16)0.f;
    }
    for (int i = tid; i < 64 * 7; i += 256) {
        int r = i / 7, c = D_IN + (i - r * 7);
        sX[r * TSTR + c] = (_Float16)0.f;
    }
    __syncthreads();
    int lm = l & 15, q = l >> 4;
    half8 a = *(const half8*)(sX + (w * 16 + lm) * TSTR + q * 8);
    const unsigned short* wT = wpkAll + 44544;
#pragma unroll
    for (int mat = 0; mat < 6; ++mat) {
        float4v acc[4];
#pragma unroll
        for (int ot = 0; ot < 4; ++ot) {
            half8 b = *(const half8*)(wT + (mat * 4 + ot) * 512 + l * 8);
            float4v z = {0.f, 0.f, 0.f, 0.f};
            acc[ot] = __builtin_amdgcn_mfma_f32_16x16x32_f16(a, b, z, 0, 0, 0);
        }
#pragma unroll
        for (int ot = 0; ot < 4; ++ot) {
            float bv = biasPad[304 + mat * 64 + ot * 16 + lm];
#pragma unroll
            for (int r = 0; r < 4; ++r)
                sO[w][(q * 4 + r) * OSTR + ot * 16 + lm] = (_Float16)(acc[ot][r] + bv);
        }
        __half* dst = ((mat & 1) ? xr3 : xl3) + (size_t)(mat >> 1) * N_NODES * 64;
#pragma unroll
        for (int it = 0; it < 2; ++it) {
            int idx = it * 64 + l;
            int rr = idx >> 3, cc = idx & 7;
            int gr = g0 + w * 16 + rr;
            if (gr < N_NODES) {
                uint4 v = *(const uint4*)&sO[w][rr * OSTR + cc * 8];
                *(uint4*)&dst[(size_t)gr * 64 + cc * 8] = v;
            }
        }
    }
}

// ---------------- GATv2 aggregation over pre-sorted lists ------------------------
// One block per (64-dst group, tag). Round-7 structure (44 VGPR — MUST stay <=64:
// crossing 64 halves the wave ceiling; round-6 measured 72 VGPR -> 29% occ, 145us).
// Degree-sorted stealing via permL. This round: packed-f32 accumulation (f2) to
// halve per-edge accumulate VALU ops (round-7 measured VALUBusy 52%).
__device__ __forceinline__ float edge_score8(uint4 u, const h2* xr, const h2* at)
{
    const h2 k2 = {(_Float16)0.2f, (_Float16)0.2f};
    float acc = 0.f;
    unsigned uu[4] = {u.x, u.y, u.z, u.w};
#pragma unroll
    for (int i = 0; i < 4; ++i) {
        h2 m = bch2(uu[i]) + xr[i];
        m = __builtin_elementwise_max(m, m * k2);
        acc = __builtin_amdgcn_fdot2(m, at[i], acc, false);
    }
    return acc;
}
__device__ __forceinline__ void accum8v(f2* O, float w, uint4 u)
{
    unsigned uu[4] = {u.x, u.y, u.z, u.w};
    f2 wv = {w, w};
#pragma unroll
    for (int i = 0; i < 4; ++i) {
        h2 xv = bch2(uu[i]);
        f2 xf = {(float)xv[0], (float)xv[1]};
        O[i] += wv * xf;                 // packed f32 fma
    }
}

__global__ __launch_bounds__(256) void bkt_gat_kernel(
    const unsigned* __restrict__ srcsS, const unsigned* __restrict__ dstartAll,
    const unsigned char* __restrict__ permAll,
    const __half* __restrict__ xl3, const __half* __restrict__ xr3,
    const float* __restrict__ att0, const float* __restrict__ att1, const float* __restrict__ att2,
    const float* __restrict__ bo0, const float* __restrict__ bo1, const float* __restrict__ bo2,
    __half* __restrict__ h16)
{
    int tag = blockIdx.y, fb = blockIdx.x;
    int cb = fb >> 2;                 // coarse bucket
    int qd = fb & 3;                  // quarter within coarse bucket
    const unsigned* srcs = srcsS + (size_t)tag * NBKT_C * BSTR_S;
    const unsigned* dstart = dstartAll + ((size_t)tag * NBKT_C + cb) * 257 + qd * 64;
    const uint4* xl4 = (const uint4*)xl3 + (size_t)tag * N_NODES * 8;
    const uint4* xr4 = (const uint4*)xr3 + (size_t)tag * N_NODES * 8;
    const float* att = (tag == 0) ? att0 : (tag == 1) ? att1 : att2;
    const float* bo  = (tag == 0) ? bo0  : (tag == 1) ? bo1  : bo2;
    int col0 = tag * 50;

    __shared__ unsigned nextD;
    __shared__ unsigned char permL[DPB];
    int tid = threadIdx.x;
    if (tid < DPB)
        permL[tid] = permAll[(((size_t)tag * NBKT_C + cb) << 8) + (qd << 6) + tid];
    if (tid == 0) nextD = 0;
    __syncthreads();

    // ---- aggregation: 32 groups x 8 lanes; work-stealing over the DPB dsts
    const int l = tid & 7;
    const int grpBase = tid & ~7;
    int c0 = 8 * l;
    h2 at[4];
#pragma unroll
    for (int i = 0; i < 4; ++i) {
        int cc = c0 + 2 * i;
        float lo = (cc < D_OUT) ? att[cc] : 0.f;
        float hi = (cc + 1 < D_OUT) ? att[cc + 1] : 0.f;
        at[i] = h2{(_Float16)lo, (_Float16)hi};
    }
    for (;;) {
        unsigned d;
        if (l == 0) d = atomicAdd(&nextD, 1u);
        d = (unsigned)__shfl((int)d, grpBase);
        if (d >= (unsigned)DPB) break;
        int pd = (int)permL[d];       // degree-sorted steal order
        int g = (cb << 8) + (qd << 6) + pd;
        if (g >= N_NODES) continue;   // tail guard
        uint4 xru = xr4[g * 8 + l];
        h2 xr[4] = {bch2(xru.x), bch2(xru.y), bch2(xru.z), bch2(xru.w)};
        uint4 xs = xl4[g * 8 + l];

        float q = edge_score8(xs, xr, at);
        q += __shfl_xor(q, 1); q += __shfl_xor(q, 2); q += __shfl_xor(q, 4);
        float S = __expf(q);                    // scores bounded: raw exp safe
        f2 O[4];
#pragma unroll
        for (int i = 0; i < 4; ++i) O[i] = f2{0.f, 0.f};
        accum8v(O, S, xs);

        unsigned j = dstart[pd], jE = dstart[pd + 1];
        if (j < jE) {
            uint4 vv = *(const uint4*)&srcs[j];        // 16B-aligned (j % 4 == 0)
            uint4 c0v = xl4[(vv.x & 0x7FFFFFFFu) + l];
            uint4 c1v = xl4[(vv.y & 0x7FFFFFFFu) + l];
            uint4 c2v = xl4[(vv.z & 0x7FFFFFFFu) + l];
            uint4 c3v = xl4[(vv.w & 0x7FFFFFFFu) + l];
            for (;;) {
                j += 4;
                bool more = j < jE;
                uint4 nv, p0v, p1v, p2v, p3v;
                if (more) {
                    nv = *(const uint4*)&srcs[j];
                    p0v = xl4[(nv.x & 0x7FFFFFFFu) + l];
                    p1v = xl4[(nv.y & 0x7FFFFFFFu) + l];
                    p2v = xl4[(nv.z & 0x7FFFFFFFu) + l];
                    p3v = xl4[(nv.w & 0x7FFFFFFFu) + l];
                }
                float p0 = edge_score8(c0v, xr, at);
                float p1 = edge_score8(c1v, xr, at);
                float p2 = edge_score8(c2v, xr, at);
                float p3 = edge_score8(c3v, xr, at);
                p0 += __shfl_xor(p0, 1); p0 += __shfl_xor(p0, 2); p0 += __shfl_xor(p0, 4);
                p1 += __shfl_xor(p1, 1); p1 += __shfl_xor(p1, 2); p1 += __shfl_xor(p1, 4);
                p2 += __shfl_xor(p2, 1); p2 += __shfl_xor(p2, 2); p2 += __shfl_xor(p2, 4);
                p3 += __shfl_xor(p3, 1); p3 += __shfl_xor(p3, 2); p3 += __shfl_xor(p3, 4);
                float w0 = (vv.x & 0x80000000u) ? 0.f : __expf(p0);
                float w1 = (vv.y & 0x80000000u) ? 0.f : __expf(p1);
                float w2 = (vv.z & 0x80000000u) ? 0.f : __expf(p2);
                float w3 = (vv.w & 0x80000000u) ? 0.f : __expf(p3);
                S += (w0 + w1) + (w2 + w3);
                accum8v(O, w0, c0v);
                accum8v(O, w1, c1v);
                accum8v(O, w2, c2v);
                accum8v(O, w3, c3v);
                if (!more) break;
                vv = nv; c0v = p0v; c1v = p1v; c2v = p2v; c3v = p3v;
            }
        }
        float inv = 1.f / (S + 1e-16f);
        size_t base = (size_t)g * 160 + col0 + c0;
#pragma unroll
        for (int i = 0; i < 4; ++i) {
            int cc = c0 + 2 * i;
            if (cc + 1 < D_OUT) {
                float blo = bo[cc], bhi = bo[cc + 1];
                float vlo = lrelu(O[i][0] * inv + blo, 0.1f);
                float vhi = lrelu(O[i][1] * inv + bhi, 0.1f);
                *(__half2*)&h16[base + 2 * i] = __floats2half2_rn(vlo, vhi);
            }
        }
    }
}

// ---------------- fused MFMA MLP head, wave-independent 16-node tiles ------------
#define HS 168

template<int NOT, int NKS, bool ACT>
__device__ __forceinline__ void head_layer(
    const _Float16* __restrict__ in, _Float16* __restrict__ outp,
    const unsigned short* __restrict__ wp, const float* __restrict__ bias, int l)
{
    const int lm = l & 15, q = l >> 4;
    const _Float16* aBase = in + lm * HS + q * 8;
#pragma unroll
    for (int ot = 0; ot < NOT; ++ot) {
        float4v acc = {0.f, 0.f, 0.f, 0.f};
        const unsigned short* bBase = wp + (ot * NKS) * 512 + l * 8;
#pragma unroll
        for (int ks = 0; ks < NKS; ++ks) {
            half8 a = *(const half8*)(aBase + ks * 32);
            half8 b = *(const half8*)(bBase + ks * 512);
            acc = __builtin_amdgcn_mfma_f32_16x16x32_f16(a, b, acc, 0, 0, 0);
        }
        float bv = bias[ot * 16 + lm];
#pragma unroll
        for (int r = 0; r < 4; ++r) {
            float v = acc[r] + bv;
            if (ACT) v = lrelu(v, 0.1f);
            outp[(q * 4 + r) * HS + ot * 16 + lm] = (_Float16)v;
        }
    }
}

__global__ __launch_bounds__(256) void mfma_head_kernel(
    const __half* __restrict__ h16,
    const unsigned short* __restrict__ wpkAll, const float* __restrict__ biasPad,
    float* __restrict__ out)
{
    __shared__ _Float16 sIn[4][16 * HS];
    __shared__ _Float16 sOut[4][16 * HS];
    int tid = threadIdx.x;
    int w = tid >> 6, l = tid & 63;
    int g0 = blockIdx.x * 64 + w * 16;

    const uint2* hq = (const uint2*)h16;
    for (int idx = l; idx < 16 * 42; idx += 64) {
        int row = idx / 42, qc = idx - row * 42;
        int gn = g0 + row;
        uint2 u = {0u, 0u};
        if (gn < N_NODES && qc < 40) {
            u = hq[(size_t)gn * 40 + qc];
            if (qc == 37) u.y = 0u;
            else if (qc > 37) { u.x = 0u; u.y = 0u; }
        }
        *(uint2*)&sIn[w][row * HS + qc * 4] = u;
    }
    __syncthreads();
    head_layer<10, 5, false>(sIn[w], sOut[w], wpkAll,         biasPad + 0,   l);
    __syncthreads();
    head_layer<6, 5, true >(sOut[w], sIn[w], wpkAll + 25600,  biasPad + 160, l);
    __syncthreads();
    head_layer<2, 3, true >(sIn[w], sOut[w], wpkAll + 40960,  biasPad + 256, l);
    __syncthreads();
    {
        const int lm = l & 15, q = l >> 4;
        float4v acc = {0.f, 0.f, 0.f, 0.f};
        half8 a = *(const half8*)(sOut[w] + lm * HS + q * 8);
        half8 b = *(const half8*)(wpkAll + 44032 + l * 8);
        acc = __builtin_amdgcn_mfma_f32_16x16x32_f16(a, b, acc, 0, 0, 0);
        if (lm < 2) {
            float bv = biasPad[288 + lm];
#pragma unroll
            for (int r = 0; r < 4; ++r) {
                int node = g0 + q * 4 + r;
                if (node < N_NODES) out[node * 2 + lm] = acc[r] + bv;
            }
        }
    }
}

extern "C" void kernel_launch(void* const* d_in, const int* in_sizes, int n_in,
                              void* d_out, int out_size, void* d_ws, size_t ws_size,
                              hipStream_t stream)
{
    const float* x = (const float*)d_in[0];
    const int* eip = (const int*)d_in[1];
    const int* eis = (const int*)d_in[2];
    const int* eiv = (const int*)d_in[3];
    const float *Wl[3], *bl[3], *Wr[3], *br[3], *att[3], *bo[3];
    for (int t = 0; t < 3; ++t) {
        int b = 4 + t * 6;
        Wl[t] = (const float*)d_in[b + 0];
        bl[t] = (const float*)d_in[b + 1];
        Wr[t] = (const float*)d_in[b + 2];
        br[t] = (const float*)d_in[b + 3];
        att[t] = (const float*)d_in[b + 4];
        bo[t] = (const float*)d_in[b + 5];
    }
    const float* projW = (const float*)d_in[22];
    const float* projb = (const float*)d_in[23];
    const float* W1 = (const float*)d_in[24];
    const float* b1 = (const float*)d_in[25];
    const float* W2 = (const float*)d_in[26];
    const float* b2 = (const float*)d_in[27];
    const float* W3 = (const float*)d_in[28];
    const float* b3 = (const float*)d_in[29];
    float* out = (float*)d_out;

    char* ws = (char*)d_ws;
    size_t off = 0;
    auto alloc = [&](size_t bytes) -> char* {
        char* p = ws + off;
        off += (bytes + 255) & ~(size_t)255;
        return p;
    };
    // xl3 has one extra zero row at absolute row index 3*N_NODES (dummy target)
    __half* xl3 = (__half*)alloc(((size_t)3 * N_NODES * 64 + 64) * 2);  // 38.4 MB
    __half* xr3 = (__half*)alloc((size_t)3 * N_NODES * 64 * 2);         // 38.4 MB
    unsigned* bucketedC = (unsigned*)alloc((size_t)3 * NBKT_C * BSTR_C * 4); // 22.5 MB
    unsigned* bcur3 = (unsigned*)alloc((size_t)3 * NBKT_C * 4);
    unsigned* srcsS = (unsigned*)alloc((size_t)3 * NBKT_C * BSTR_S * 4); // 26.1 MB
    unsigned* dstartAll = (unsigned*)alloc((size_t)3 * NBKT_C * 257 * 4); // 1.2 MB
    unsigned char* permAll = (unsigned char*)alloc((size_t)3 * NBKT_C * 256); // 0.3 MB
    __half* h16 = (__half*)alloc((size_t)N_NODES * 160 * 2);            // 32 MB
    unsigned short* wpkAll = (unsigned short*)alloc(56832 * 2);
    float* biasPad = (float*)alloc(688 * 4);

    hipMemsetAsync(bcur3, 0, (size_t)3 * NBKT_C * 4, stream);
    pack_all_kernel<<<226, 256, 0, stream>>>(
        projW, W1, W2, W3, projb, b1, b2, b3,
        Wl[0], Wr[0], Wl[1], Wr[1], Wl[2], Wr[2],
        bl[0], br[0], bl[1], br[1], bl[2], br[2],
        wpkAll, biasPad, xl3);

    bkt_scatter_kernel<<<dim3(NBLK_E, 3), 256, 0, stream>>>(eip, eis, eiv, bcur3, bucketedC);

    bkt_sort_kernel<<<dim3(NBKT_C, 3), 256, 0, stream>>>(bucketedC, bcur3, srcsS, dstartAll, permAll);

    transform_mfma_kernel<<<(N_NODES + 63) / 64, 256, 0, stream>>>(
        x, wpkAll, biasPad, xl3, xr3);

    bkt_gat_kernel<<<dim3(NBKT_F, 3), 256, 0, stream>>>(
        srcsS, dstartAll, permAll, xl3, xr3,
        att[0], att[1], att[2], bo[0], bo[1], bo[2], h16);

    mfma_head_kernel<<<(N_NODES + 63) / 64, 256, 0, stream>>>(h16, wpkAll, biasPad, out);
}

// Round 9
// 365.996 us; speedup vs baseline: 1.1495x; 1.0652x over previous
//
#include <hip/hip_runtime.h>
#include <hip/hip_fp16.h>

#define N_NODES 100000
#define N_EDGES 1600000
#define D_IN 25
#define D_OUT 50
// scatter granularity: coarse buckets of 256 dsts (good write coalescing)
#define NBKT_C 391      // ceil(100000/256)
#define BSTR_C 4800     // mean 4096 + ~11 sigma
#define BSTR_S 5568     // sorted stride: BSTR_C + 256*3 padding (hard bound)
// gat granularity: 64 dsts per block; 4 gat blocks per coarse bucket
#define DPB 64
#define NBKT_F 1563     // ceil(100000/64)
#define EPB 8192        // edges per block in scatter pass
#define NBLK_E 196      // ceil(N_EDGES/EPB)
#define SCT_T 1024      // scatter block threads (16 waves: round-2 PMC showed
                        // 2% VALUBusy / 20% occupancy at 4 waves — latency-starved)

typedef __attribute__((ext_vector_type(8))) _Float16 half8;
typedef __attribute__((ext_vector_type(2))) _Float16 h2;
typedef __attribute__((ext_vector_type(4))) float float4v;
typedef __attribute__((ext_vector_type(2))) float f2;

__device__ __forceinline__ float lrelu(float x, float a) { return fmaxf(x, a * x); }
__device__ __forceinline__ h2 bch2(unsigned u) { return __builtin_bit_cast(h2, u); }

// ---------------- fused bucket scatter: LDS hist -> global reserve -> write ------
// Coarse 256-dst buckets keep per-block per-bucket runs ~21 edges = 84B
// contiguous. 1024-thread blocks: same EPB (same write runs), 4x wave residency.
__global__ __launch_bounds__(SCT_T) void bkt_scatter_kernel(
    const int* __restrict__ eip, const int* __restrict__ eis, const int* __restrict__ eiv,
    unsigned* __restrict__ bcur3, unsigned* __restrict__ bucketedC)
{
    int t = blockIdx.y;
    const int* ei = (t == 0) ? eip : ((t == 1) ? eis : eiv);
    unsigned* bcur = bcur3 + t * NBKT_C;
    unsigned* bucketed = bucketedC + (size_t)t * NBKT_C * BSTR_C;
    __shared__ unsigned h[NBKT_C];
    __shared__ unsigned cur[NBKT_C];
    int tid = threadIdx.x;
    for (int b = tid; b < NBKT_C; b += SCT_T) h[b] = 0;
    __syncthreads();
#pragma unroll
    for (int i = 0; i < EPB / (SCT_T * 4); ++i) {
        int e = blockIdx.x * EPB + (i * SCT_T + tid) * 4;
        if (e < N_EDGES) {               // N_EDGES % 4 == 0: whole int4 valid
            int4 d4 = *(const int4*)&ei[N_EDGES + e];
            atomicAdd(&h[(unsigned)d4.x >> 8], 1u);
            atomicAdd(&h[(unsigned)d4.y >> 8], 1u);
            atomicAdd(&h[(unsigned)d4.z >> 8], 1u);
            atomicAdd(&h[(unsigned)d4.w >> 8], 1u);
        }
    }
    __syncthreads();
    for (int b = tid; b < NBKT_C; b += SCT_T)
        cur[b] = (unsigned)b * BSTR_C + (h[b] ? atomicAdd(&bcur[b], h[b]) : 0u);
    __syncthreads();
#pragma unroll
    for (int i = 0; i < EPB / (SCT_T * 4); ++i) {
        int e = blockIdx.x * EPB + (i * SCT_T + tid) * 4;
        if (e < N_EDGES) {
            int4 s4 = *(const int4*)&ei[e];
            int4 d4 = *(const int4*)&ei[N_EDGES + e];
            int ss[4] = {s4.x, s4.y, s4.z, s4.w};
            int dd[4] = {d4.x, d4.y, d4.z, d4.w};
#pragma unroll
            for (int k = 0; k < 4; ++k) {
                unsigned d = (unsigned)dd[k];
                unsigned b = d >> 8;
                unsigned r = atomicAdd(&cur[b], 1u);
                if (r < (b + 1u) * BSTR_C)   // overflow guard (11-sigma margin)
                    bucketed[r] = ((d & 255u) << 17) | (unsigned)ss[k];
            }
        }
    }
}

// ---------------- counting sort: coarse bucket -> per-dst lists + offsets --------
// One block per (coarse bucket, tag). Full 256-dst sort in LDS, per-dst lists
// padded to x4 with flagged dummy zero-row entries, written out coalesced.
// Also emits a within-quarter DESCENDING-DEGREE permutation: gat's 8-lane groups
// steal dsts in that order so concurrently-processed lists have similar length.
__global__ __launch_bounds__(256) void bkt_sort_kernel(
    const unsigned* __restrict__ bucketedC, const unsigned* __restrict__ bcur3,
    unsigned* __restrict__ srcsS, unsigned* __restrict__ dstartAll,
    unsigned char* __restrict__ permAll)
{
    int tag = blockIdx.y, cb = blockIdx.x;
    const unsigned* in = bucketedC + ((size_t)tag * NBKT_C + cb) * BSTR_C;
    unsigned* outp = srcsS + (size_t)tag * NBKT_C * BSTR_S + (size_t)cb * BSTR_S;
    unsigned* dstart = dstartAll + ((size_t)tag * NBKT_C + cb) * 257;
    unsigned char* perm = permAll + (((size_t)tag * NBKT_C + cb) << 8);
    __shared__ unsigned hist[256];
    __shared__ unsigned cnt2[256];
    __shared__ unsigned cur[256];
    __shared__ __align__(16) unsigned sbuf[BSTR_S];
    __shared__ unsigned totS;
    int tid = threadIdx.x;
    unsigned cnt = bcur3[tag * NBKT_C + cb];
    if (cnt > BSTR_C) cnt = BSTR_C;
    hist[tid] = 0;
    __syncthreads();
    for (unsigned i = tid; i < cnt; i += 256) atomicAdd(&hist[in[i] >> 17], 1u);
    __syncthreads();
    unsigned c = hist[tid];
    cnt2[tid] = c;
    unsigned pc = (c + 3u) & ~3u;        // pad each dst's list to multiple of 4
    hist[tid] = pc;
    __syncthreads();
    for (int off = 1; off < 256; off <<= 1) {   // inclusive scan of padded counts
        unsigned v = (tid >= off) ? hist[tid - off] : 0u;
        __syncthreads();
        hist[tid] += v;
        __syncthreads();
    }
    unsigned excl = hist[tid] - pc;
    cur[tid] = excl;
    dstart[tid] = (unsigned)cb * BSTR_S + excl;   // absolute within-tag offset
    if (tid == 255) { dstart[256] = (unsigned)cb * BSTR_S + hist[255]; totS = hist[255]; }
    {   // within-quarter descending-degree rank (ties broken by index) -> perm
        int q0 = tid & ~63;
        int rank = 0;
        for (int j = 0; j < 64; ++j) {
            unsigned cj = cnt2[q0 + j];
            rank += (cj > c) || (cj == c && (q0 + j) < tid);
        }
        perm[q0 + rank] = (unsigned char)(tid & 63);
    }
    __syncthreads();
    for (unsigned i = tid; i < cnt; i += 256) {   // scatter into LDS sorted order
        unsigned w = in[i];
        unsigned r = atomicAdd(&cur[w >> 17], 1u);
        sbuf[r] = (w & 0x1FFFFu) << 3;            // pre-scaled uint4 row index
    }
    {
        const unsigned DUMMY = 0x80000000u | ((unsigned)(3 * N_NODES) << 3);
        for (unsigned k = c; k < pc; ++k) sbuf[excl + k] = DUMMY;  // disjoint slots
    }
    __syncthreads();
    unsigned tot = totS;                 // <= BSTR_S by construction
    for (unsigned i = tid; i < tot; i += 256) outp[i] = sbuf[i];
}

// ---------------- pack: head B-fragments (fp16) + transform weights + biases -----
__device__ __forceinline__ void pack_seg(
    const float* __restrict__ W, unsigned short* __restrict__ outp,
    int K, int O, int NKS, int idx)
{
    int f = idx >> 9, r = idx & 511;
    int l = r >> 3, j = r & 7;
    int ot = f / NKS, ks = f - ot * NKS;
    int k = ks * 32 + (l >> 4) * 8 + j;
    int o = ot * 16 + (l & 15);
    float val = (k < K && o < O) ? W[k * O + o] : 0.f;
    outp[idx] = __half_as_ushort(__float2half_rn(val));
}

__global__ __launch_bounds__(256) void pack_all_kernel(
    const float* __restrict__ projW, const float* __restrict__ W1,
    const float* __restrict__ W2, const float* __restrict__ W3,
    const float* __restrict__ b0, const float* __restrict__ b1,
    const float* __restrict__ b2, const float* __restrict__ b3,
    const float* __restrict__ Wl0, const float* __restrict__ Wr0,
    const float* __restrict__ Wl1, const float* __restrict__ Wr1,
    const float* __restrict__ Wl2, const float* __restrict__ Wr2,
    const float* __restrict__ bl0, const float* __restrict__ br0,
    const float* __restrict__ bl1, const float* __restrict__ br1,
    const float* __restrict__ bl2, const float* __restrict__ br2,
    unsigned short* __restrict__ wpkAll, float* __restrict__ biasPad,
    __half* __restrict__ xl3)
{
    int gid = blockIdx.x * 256 + threadIdx.x;
    if (gid < 25600) pack_seg(projW, wpkAll, 150, 150, 5, gid);
    else if (gid < 40960) pack_seg(W1, wpkAll + 25600, 150, 75, 5, gid - 25600);
    else if (gid < 44032) pack_seg(W2, wpkAll + 40960, 75, 30, 3, gid - 40960);
    else if (gid < 44544) pack_seg(W3, wpkAll + 44032, 30, 2, 1, gid - 44032);
    else if (gid < 56832) {
        int t = gid - 44544;
        int mat = t >> 11, idx = t & 2047;
        const float* Wm = (mat == 0) ? Wl0 : (mat == 1) ? Wr0 : (mat == 2) ? Wl1
                        : (mat == 3) ? Wr1 : (mat == 4) ? Wl2 : Wr2;
        int ot = idx >> 9, r = idx & 511;
        int l = r >> 3, j = r & 7;
        int k = (l >> 4) * 8 + j;
        int o = ot * 16 + (l & 15);
        float val = (k < D_IN && o < D_OUT) ? Wm[k * D_OUT + o] : 0.f;
        wpkAll[44544 + t] = __half_as_ushort(__float2half_rn(val));
    } else if (gid < 57520) {
        int t = gid - 56832;
        float v;
        if (t < 304) {
            if (t < 160) v = (t < 150) ? b0[t] : 0.f;
            else if (t < 256) { int i = t - 160; v = (i < 75) ? b1[i] : 0.f; }
            else if (t < 288) { int i = t - 256; v = (i < 30) ? b2[i] : 0.f; }
            else { int i = t - 288; v = (i < 2) ? b3[i] : 0.f; }
        } else {
            int ii = t - 304;
            int mat = ii >> 6, o = ii & 63;
            const float* bm = (mat == 0) ? bl0 : (mat == 1) ? br0 : (mat == 2) ? bl1
                            : (mat == 3) ? br1 : (mat == 4) ? bl2 : br2;
            v = (o < D_OUT) ? bm[o] : 0.f;
        }
        biasPad[t] = v;
    } else if (gid < 57584) {
        // zero row at absolute row 3*N_NODES: dummy-edge gather target
        xl3[(size_t)3 * N_NODES * 64 + (gid - 57520)] = __ushort_as_half((unsigned short)0);
    }
}

// ---------------- MFMA node transform: xl/xr (6 mats) via 16x16x32 f16 -----------
#define TSTR 32
#define OSTR 72

__global__ __launch_bounds__(256) void transform_mfma_kernel(
    const float* __restrict__ x,
    const unsigned short* __restrict__ wpkAll, const float* __restrict__ biasPad,
    __half* __restrict__ xl3, __half* __restrict__ xr3)
{
    __shared__ _Float16 sX[64 * TSTR];
    __shared__ _Float16 sO[4][16 * OSTR];
    int tid = threadIdx.x;
    int w = tid >> 6, l = tid & 63;
    int g0 = blockIdx.x * 64;
    for (int i = tid; i < 64 * D_IN; i += 256) {
        int r = i / D_IN, c = i - r * D_IN;
        int gr = g0 + r;
        sX[r * TSTR + c] = (gr < N_NODES) ? (_Float16)x[(size_t)gr * D_IN + c] : (_Float16)0.f;
    }
    for (int i = tid; i < 64 * 7; i += 256) {
        int r = i / 7, c = D_IN + (i - r * 7);
        sX[r * TSTR + c] = (_Float16)0.f;
    }
    __syncthreads();
    int lm = l & 15, q = l >> 4;
    half8 a = *(const half8*)(sX + (w * 16 + lm) * TSTR + q * 8);
    const unsigned short* wT = wpkAll + 44544;
#pragma unroll
    for (int mat = 0; mat < 6; ++mat) {
        float4v acc[4];
#pragma unroll
        for (int ot = 0; ot < 4; ++ot) {
            half8 b = *(const half8*)(wT + (mat * 4 + ot) * 512 + l * 8);
            float4v z = {0.f, 0.f, 0.f, 0.f};
            acc[ot] = __builtin_amdgcn_mfma_f32_16x16x32_f16(a, b, z, 0, 0, 0);
        }
#pragma unroll
        for (int ot = 0; ot < 4; ++ot) {
            float bv = biasPad[304 + mat * 64 + ot * 16 + lm];
#pragma unroll
            for (int r = 0; r < 4; ++r)
                sO[w][(q * 4 + r) * OSTR + ot * 16 + lm] = (_Float16)(acc[ot][r] + bv);
        }
        __half* dst = ((mat & 1) ? xr3 : xl3) + (size_t)(mat >> 1) * N_NODES * 64;
#pragma unroll
        for (int it = 0; it < 2; ++it) {
            int idx = it * 64 + l;
            int rr = idx >> 3, cc = idx & 7;
            int gr = g0 + w * 16 + rr;
            if (gr < N_NODES) {
                uint4 v = *(const uint4*)&sO[w][rr * OSTR + cc * 8];
                *(uint4*)&dst[(size_t)gr * 64 + cc * 8] = v;
            }
        }
    }
}

// ---------------- GATv2 aggregation over pre-sorted lists ------------------------
// One block per (64-dst group, tag). 48 VGPR — MUST stay <=64: crossing 64 halves
// the wave ceiling (round-6: 72 VGPR -> 29% occ, 145us). Degree-sorted stealing
// via permL; packed-f32 accumulation (round-8: 115 -> 110.5us).
__device__ __forceinline__ float edge_score8(uint4 u, const h2* xr, const h2* at)
{
    const h2 k2 = {(_Float16)0.2f, (_Float16)0.2f};
    float acc = 0.f;
    unsigned uu[4] = {u.x, u.y, u.z, u.w};
#pragma unroll
    for (int i = 0; i < 4; ++i) {
        h2 m = bch2(uu[i]) + xr[i];
        m = __builtin_elementwise_max(m, m * k2);
        acc = __builtin_amdgcn_fdot2(m, at[i], acc, false);
    }
    return acc;
}
__device__ __forceinline__ void accum8v(f2* O, float w, uint4 u)
{
    unsigned uu[4] = {u.x, u.y, u.z, u.w};
    f2 wv = {w, w};
#pragma unroll
    for (int i = 0; i < 4; ++i) {
        h2 xv = bch2(uu[i]);
        f2 xf = {(float)xv[0], (float)xv[1]};
        O[i] += wv * xf;                 // packed f32 fma
    }
}

__global__ __launch_bounds__(256) void bkt_gat_kernel(
    const unsigned* __restrict__ srcsS, const unsigned* __restrict__ dstartAll,
    const unsigned char* __restrict__ permAll,
    const __half* __restrict__ xl3, const __half* __restrict__ xr3,
    const float* __restrict__ att0, const float* __restrict__ att1, const float* __restrict__ att2,
    const float* __restrict__ bo0, const float* __restrict__ bo1, const float* __restrict__ bo2,
    __half* __restrict__ h16)
{
    int tag = blockIdx.y, fb = blockIdx.x;
    int cb = fb >> 2;                 // coarse bucket
    int qd = fb & 3;                  // quarter within coarse bucket
    const unsigned* srcs = srcsS + (size_t)tag * NBKT_C * BSTR_S;
    const unsigned* dstart = dstartAll + ((size_t)tag * NBKT_C + cb) * 257 + qd * 64;
    const uint4* xl4 = (const uint4*)xl3 + (size_t)tag * N_NODES * 8;
    const uint4* xr4 = (const uint4*)xr3 + (size_t)tag * N_NODES * 8;
    const float* att = (tag == 0) ? att0 : (tag == 1) ? att1 : att2;
    const float* bo  = (tag == 0) ? bo0  : (tag == 1) ? bo1  : bo2;
    int col0 = tag * 50;

    __shared__ unsigned nextD;
    __shared__ unsigned char permL[DPB];
    int tid = threadIdx.x;
    if (tid < DPB)
        permL[tid] = permAll[(((size_t)tag * NBKT_C + cb) << 8) + (qd << 6) + tid];
    if (tid == 0) nextD = 0;
    __syncthreads();

    // ---- aggregation: 32 groups x 8 lanes; work-stealing over the DPB dsts
    const int l = tid & 7;
    const int grpBase = tid & ~7;
    int c0 = 8 * l;
    h2 at[4];
#pragma unroll
    for (int i = 0; i < 4; ++i) {
        int cc = c0 + 2 * i;
        float lo = (cc < D_OUT) ? att[cc] : 0.f;
        float hi = (cc + 1 < D_OUT) ? att[cc + 1] : 0.f;
        at[i] = h2{(_Float16)lo, (_Float16)hi};
    }
    for (;;) {
        unsigned d;
        if (l == 0) d = atomicAdd(&nextD, 1u);
        d = (unsigned)__shfl((int)d, grpBase);
        if (d >= (unsigned)DPB) break;
        int pd = (int)permL[d];       // degree-sorted steal order
        int g = (cb << 8) + (qd << 6) + pd;
        if (g >= N_NODES) continue;   // tail guard
        uint4 xru = xr4[g * 8 + l];
        h2 xr[4] = {bch2(xru.x), bch2(xru.y), bch2(xru.z), bch2(xru.w)};
        uint4 xs = xl4[g * 8 + l];

        float q = edge_score8(xs, xr, at);
        q += __shfl_xor(q, 1); q += __shfl_xor(q, 2); q += __shfl_xor(q, 4);
        float S = __expf(q);                    // scores bounded: raw exp safe
        f2 O[4];
#pragma unroll
        for (int i = 0; i < 4; ++i) O[i] = f2{0.f, 0.f};
        accum8v(O, S, xs);

        unsigned j = dstart[pd], jE = dstart[pd + 1];
        if (j < jE) {
            uint4 vv = *(const uint4*)&srcs[j];        // 16B-aligned (j % 4 == 0)
            uint4 c0v = xl4[(vv.x & 0x7FFFFFFFu) + l];
            uint4 c1v = xl4[(vv.y & 0x7FFFFFFFu) + l];
            uint4 c2v = xl4[(vv.z & 0x7FFFFFFFu) + l];
            uint4 c3v = xl4[(vv.w & 0x7FFFFFFFu) + l];
            for (;;) {
                j += 4;
                bool more = j < jE;
                uint4 nv, p0v, p1v, p2v, p3v;
                if (more) {
                    nv = *(const uint4*)&srcs[j];
                    p0v = xl4[(nv.x & 0x7FFFFFFFu) + l];
                    p1v = xl4[(nv.y & 0x7FFFFFFFu) + l];
                    p2v = xl4[(nv.z & 0x7FFFFFFFu) + l];
                    p3v = xl4[(nv.w & 0x7FFFFFFFu) + l];
                }
                float p0 = edge_score8(c0v, xr, at);
                float p1 = edge_score8(c1v, xr, at);
                float p2 = edge_score8(c2v, xr, at);
                float p3 = edge_score8(c3v, xr, at);
                p0 += __shfl_xor(p0, 1); p0 += __shfl_xor(p0, 2); p0 += __shfl_xor(p0, 4);
                p1 += __shfl_xor(p1, 1); p1 += __shfl_xor(p1, 2); p1 += __shfl_xor(p1, 4);
                p2 += __shfl_xor(p2, 1); p2 += __shfl_xor(p2, 2); p2 += __shfl_xor(p2, 4);
                p3 += __shfl_xor(p3, 1); p3 += __shfl_xor(p3, 2); p3 += __shfl_xor(p3, 4);
                float w0 = (vv.x & 0x80000000u) ? 0.f : __expf(p0);
                float w1 = (vv.y & 0x80000000u) ? 0.f : __expf(p1);
                float w2 = (vv.z & 0x80000000u) ? 0.f : __expf(p2);
                float w3 = (vv.w & 0x80000000u) ? 0.f : __expf(p3);
                S += (w0 + w1) + (w2 + w3);
                accum8v(O, w0, c0v);
                accum8v(O, w1, c1v);
                accum8v(O, w2, c2v);
                accum8v(O, w3, c3v);
                if (!more) break;
                vv = nv; c0v = p0v; c1v = p1v; c2v = p2v; c3v = p3v;
            }
        }
        float inv = 1.f / (S + 1e-16f);
        size_t base = (size_t)g * 160 + col0 + c0;
#pragma unroll
        for (int i = 0; i < 4; ++i) {
            int cc = c0 + 2 * i;
            if (cc + 1 < D_OUT) {
                float blo = bo[cc], bhi = bo[cc + 1];
                float vlo = lrelu(O[i][0] * inv + blo, 0.1f);
                float vhi = lrelu(O[i][1] * inv + bhi, 0.1f);
                *(__half2*)&h16[base + 2 * i] = __floats2half2_rn(vlo, vhi);
            }
        }
    }
}

// ---------------- fused MFMA MLP head, wave-independent 16-node tiles ------------
#define HS 168

template<int NOT, int NKS, bool ACT>
__device__ __forceinline__ void head_layer(
    const _Float16* __restrict__ in, _Float16* __restrict__ outp,
    const unsigned short* __restrict__ wp, const float* __restrict__ bias, int l)
{
    const int lm = l & 15, q = l >> 4;
    const _Float16* aBase = in + lm * HS + q * 8;
#pragma unroll
    for (int ot = 0; ot < NOT; ++ot) {
        float4v acc = {0.f, 0.f, 0.f, 0.f};
        const unsigned short* bBase = wp + (ot * NKS) * 512 + l * 8;
#pragma unroll
        for (int ks = 0; ks < NKS; ++ks) {
            half8 a = *(const half8*)(aBase + ks * 32);
            half8 b = *(const half8*)(bBase + ks * 512);
            acc = __builtin_amdgcn_mfma_f32_16x16x32_f16(a, b, acc, 0, 0, 0);
        }
        float bv = bias[ot * 16 + lm];
#pragma unroll
        for (int r = 0; r < 4; ++r) {
            float v = acc[r] + bv;
            if (ACT) v = lrelu(v, 0.1f);
            outp[(q * 4 + r) * HS + ot * 16 + lm] = (_Float16)v;
        }
    }
}

__global__ __launch_bounds__(256) void mfma_head_kernel(
    const __half* __restrict__ h16,
    const unsigned short* __restrict__ wpkAll, const float* __restrict__ biasPad,
    float* __restrict__ out)
{
    __shared__ _Float16 sIn[4][16 * HS];
    __shared__ _Float16 sOut[4][16 * HS];
    int tid = threadIdx.x;
    int w = tid >> 6, l = tid & 63;
    int g0 = blockIdx.x * 64 + w * 16;

    const uint2* hq = (const uint2*)h16;
    for (int idx = l; idx < 16 * 42; idx += 64) {
        int row = idx / 42, qc = idx - row * 42;
        int gn = g0 + row;
        uint2 u = {0u, 0u};
        if (gn < N_NODES && qc < 40) {
            u = hq[(size_t)gn * 40 + qc];
            if (qc == 37) u.y = 0u;
            else if (qc > 37) { u.x = 0u; u.y = 0u; }
        }
        *(uint2*)&sIn[w][row * HS + qc * 4] = u;
    }
    __syncthreads();
    head_layer<10, 5, false>(sIn[w], sOut[w], wpkAll,         biasPad + 0,   l);
    __syncthreads();
    head_layer<6, 5, true >(sOut[w], sIn[w], wpkAll + 25600,  biasPad + 160, l);
    __syncthreads();
    head_layer<2, 3, true >(sIn[w], sOut[w], wpkAll + 40960,  biasPad + 256, l);
    __syncthreads();
    {
        const int lm = l & 15, q = l >> 4;
        float4v acc = {0.f, 0.f, 0.f, 0.f};
        half8 a = *(const half8*)(sOut[w] + lm * HS + q * 8);
        half8 b = *(const half8*)(wpkAll + 44032 + l * 8);
        acc = __builtin_amdgcn_mfma_f32_16x16x32_f16(a, b, acc, 0, 0, 0);
        if (lm < 2) {
            float bv = biasPad[288 + lm];
#pragma unroll
            for (int r = 0; r < 4; ++r) {
                int node = g0 + q * 4 + r;
                if (node < N_NODES) out[node * 2 + lm] = acc[r] + bv;
            }
        }
    }
}

extern "C" void kernel_launch(void* const* d_in, const int* in_sizes, int n_in,
                              void* d_out, int out_size, void* d_ws, size_t ws_size,
                              hipStream_t stream)
{
    const float* x = (const float*)d_in[0];
    const int* eip = (const int*)d_in[1];
    const int* eis = (const int*)d_in[2];
    const int* eiv = (const int*)d_in[3];
    const float *Wl[3], *bl[3], *Wr[3], *br[3], *att[3], *bo[3];
    for (int t = 0; t < 3; ++t) {
        int b = 4 + t * 6;
        Wl[t] = (const float*)d_in[b + 0];
        bl[t] = (const float*)d_in[b + 1];
        Wr[t] = (const float*)d_in[b + 2];
        br[t] = (const float*)d_in[b + 3];
        att[t] = (const float*)d_in[b + 4];
        bo[t] = (const float*)d_in[b + 5];
    }
    const float* projW = (const float*)d_in[22];
    const float* projb = (const float*)d_in[23];
    const float* W1 = (const float*)d_in[24];
    const float* b1 = (const float*)d_in[25];
    const float* W2 = (const float*)d_in[26];
    const float* b2 = (const float*)d_in[27];
    const float* W3 = (const float*)d_in[28];
    const float* b3 = (const float*)d_in[29];
    float* out = (float*)d_out;

    char* ws = (char*)d_ws;
    size_t off = 0;
    auto alloc = [&](size_t bytes) -> char* {
        char* p = ws + off;
        off += (bytes + 255) & ~(size_t)255;
        return p;
    };
    // xl3 has one extra zero row at absolute row index 3*N_NODES (dummy target)
    __half* xl3 = (__half*)alloc(((size_t)3 * N_NODES * 64 + 64) * 2);  // 38.4 MB
    __half* xr3 = (__half*)alloc((size_t)3 * N_NODES * 64 * 2);         // 38.4 MB
    unsigned* bucketedC = (unsigned*)alloc((size_t)3 * NBKT_C * BSTR_C * 4); // 22.5 MB
    unsigned* bcur3 = (unsigned*)alloc((size_t)3 * NBKT_C * 4);
    unsigned* srcsS = (unsigned*)alloc((size_t)3 * NBKT_C * BSTR_S * 4); // 26.1 MB
    unsigned* dstartAll = (unsigned*)alloc((size_t)3 * NBKT_C * 257 * 4); // 1.2 MB
    unsigned char* permAll = (unsigned char*)alloc((size_t)3 * NBKT_C * 256); // 0.3 MB
    __half* h16 = (__half*)alloc((size_t)N_NODES * 160 * 2);            // 32 MB
    unsigned short* wpkAll = (unsigned short*)alloc(56832 * 2);
    float* biasPad = (float*)alloc(688 * 4);

    hipMemsetAsync(bcur3, 0, (size_t)3 * NBKT_C * 4, stream);
    pack_all_kernel<<<226, 256, 0, stream>>>(
        projW, W1, W2, W3, projb, b1, b2, b3,
        Wl[0], Wr[0], Wl[1], Wr[1], Wl[2], Wr[2],
        bl[0], br[0], bl[1], br[1], bl[2], br[2],
        wpkAll, biasPad, xl3);

    bkt_scatter_kernel<<<dim3(NBLK_E, 3), SCT_T, 0, stream>>>(eip, eis, eiv, bcur3, bucketedC);

    bkt_sort_kernel<<<dim3(NBKT_C, 3), 256, 0, stream>>>(bucketedC, bcur3, srcsS, dstartAll, permAll);

    transform_mfma_kernel<<<(N_NODES + 63) / 64, 256, 0, stream>>>(
        x, wpkAll, biasPad, xl3, xr3);

    bkt_gat_kernel<<<dim3(NBKT_F, 3), 256, 0, stream>>>(
        srcsS, dstartAll, permAll, xl3, xr3,
        att[0], att[1], att[2], bo[0], bo[1], bo[2], h16);

    mfma_head_kernel<<<(N_NODES + 63) / 64, 256, 0, stream>>>(h16, wpkAll, biasPad, out);
}

// Round 11
// 353.527 us; speedup vs baseline: 1.1901x; 1.0353x over previous
//
#include <hip/hip_runtime.h>
#include <hip/hip_fp16.h>

#define N_NODES 100000
#define N_EDGES 1600000
#define D_IN 25
#define D_OUT 50
// scatter granularity: coarse buckets of 256 dsts (good write coalescing)
#define NBKT_C 391      // ceil(100000/256)
#define BSTR_C 4800     // mean 4096 + ~11 sigma
#define BSTR_S 5568     // sorted stride: BSTR_C + 256*3 padding (hard bound)
// gat granularity: 64 dsts per block; 4 gat blocks per coarse bucket
#define DPB 64
#define NBKT_F 1563     // ceil(100000/64)
#define EPB 8192        // edges per block in scatter pass
#define NBLK_E 196      // ceil(N_EDGES/EPB)
#define SCT_T 1024      // scatter block threads (16 waves: round-2 PMC showed
                        // 2% VALUBusy / 20% occupancy at 4 waves — latency-starved)

typedef __attribute__((ext_vector_type(8))) _Float16 half8;
typedef __attribute__((ext_vector_type(2))) _Float16 h2;
typedef __attribute__((ext_vector_type(4))) float float4v;
typedef __attribute__((ext_vector_type(2))) float f2;

__device__ __forceinline__ float lrelu(float x, float a) { return fmaxf(x, a * x); }
__device__ __forceinline__ h2 bch2(unsigned u) { return __builtin_bit_cast(h2, u); }

// ---------------- fused bucket scatter: LDS hist -> global reserve -> write ------
// Coarse 256-dst buckets keep per-block per-bucket runs ~21 edges = 84B
// contiguous. 1024-thread blocks: same EPB (same write runs), 4x wave residency
// (round 9: total 390 -> 366us from this change alone).
__global__ __launch_bounds__(SCT_T) void bkt_scatter_kernel(
    const int* __restrict__ eip, const int* __restrict__ eis, const int* __restrict__ eiv,
    unsigned* __restrict__ bcur3, unsigned* __restrict__ bucketedC)
{
    int t = blockIdx.y;
    const int* ei = (t == 0) ? eip : ((t == 1) ? eis : eiv);
    unsigned* bcur = bcur3 + t * NBKT_C;
    unsigned* bucketed = bucketedC + (size_t)t * NBKT_C * BSTR_C;
    __shared__ unsigned h[NBKT_C];
    __shared__ unsigned cur[NBKT_C];
    int tid = threadIdx.x;
    for (int b = tid; b < NBKT_C; b += SCT_T) h[b] = 0;
    __syncthreads();
#pragma unroll
    for (int i = 0; i < EPB / (SCT_T * 4); ++i) {
        int e = blockIdx.x * EPB + (i * SCT_T + tid) * 4;
        if (e < N_EDGES) {               // N_EDGES % 4 == 0: whole int4 valid
            int4 d4 = *(const int4*)&ei[N_EDGES + e];
            atomicAdd(&h[(unsigned)d4.x >> 8], 1u);
            atomicAdd(&h[(unsigned)d4.y >> 8], 1u);
            atomicAdd(&h[(unsigned)d4.z >> 8], 1u);
            atomicAdd(&h[(unsigned)d4.w >> 8], 1u);
        }
    }
    __syncthreads();
    for (int b = tid; b < NBKT_C; b += SCT_T)
        cur[b] = (unsigned)b * BSTR_C + (h[b] ? atomicAdd(&bcur[b], h[b]) : 0u);
    __syncthreads();
#pragma unroll
    for (int i = 0; i < EPB / (SCT_T * 4); ++i) {
        int e = blockIdx.x * EPB + (i * SCT_T + tid) * 4;
        if (e < N_EDGES) {
            int4 s4 = *(const int4*)&ei[e];
            int4 d4 = *(const int4*)&ei[N_EDGES + e];
            int ss[4] = {s4.x, s4.y, s4.z, s4.w};
            int dd[4] = {d4.x, d4.y, d4.z, d4.w};
#pragma unroll
            for (int k = 0; k < 4; ++k) {
                unsigned d = (unsigned)dd[k];
                unsigned b = d >> 8;
                unsigned r = atomicAdd(&cur[b], 1u);
                if (r < (b + 1u) * BSTR_C)   // overflow guard (11-sigma margin)
                    bucketed[r] = ((d & 255u) << 17) | (unsigned)ss[k];
            }
        }
    }
}

// ---------------- counting sort: coarse bucket -> per-dst lists + offsets --------
// One block per (coarse bucket, tag). Full 256-dst sort in LDS, per-dst lists
// padded to x4 with flagged dummy zero-row entries, written out coalesced.
// Also emits a within-quarter DESCENDING-DEGREE permutation: gat's 8-lane groups
// steal dsts in that order so concurrently-processed lists have similar length.
__global__ __launch_bounds__(256) void bkt_sort_kernel(
    const unsigned* __restrict__ bucketedC, const unsigned* __restrict__ bcur3,
    unsigned* __restrict__ srcsS, unsigned* __restrict__ dstartAll,
    unsigned char* __restrict__ permAll)
{
    int tag = blockIdx.y, cb = blockIdx.x;
    const unsigned* in = bucketedC + ((size_t)tag * NBKT_C + cb) * BSTR_C;
    unsigned* outp = srcsS + (size_t)tag * NBKT_C * BSTR_S + (size_t)cb * BSTR_S;
    unsigned* dstart = dstartAll + ((size_t)tag * NBKT_C + cb) * 257;
    unsigned char* perm = permAll + (((size_t)tag * NBKT_C + cb) << 8);
    __shared__ unsigned hist[256];
    __shared__ unsigned cnt2[256];
    __shared__ unsigned cur[256];
    __shared__ __align__(16) unsigned sbuf[BSTR_S];
    __shared__ unsigned totS;
    int tid = threadIdx.x;
    unsigned cnt = bcur3[tag * NBKT_C + cb];
    if (cnt > BSTR_C) cnt = BSTR_C;
    hist[tid] = 0;
    __syncthreads();
    for (unsigned i = tid; i < cnt; i += 256) atomicAdd(&hist[in[i] >> 17], 1u);
    __syncthreads();
    unsigned c = hist[tid];
    cnt2[tid] = c;
    unsigned pc = (c + 3u) & ~3u;        // pad each dst's list to multiple of 4
    hist[tid] = pc;
    __syncthreads();
    for (int off = 1; off < 256; off <<= 1) {   // inclusive scan of padded counts
        unsigned v = (tid >= off) ? hist[tid - off] : 0u;
        __syncthreads();
        hist[tid] += v;
        __syncthreads();
    }
    unsigned excl = hist[tid] - pc;
    cur[tid] = excl;
    dstart[tid] = (unsigned)cb * BSTR_S + excl;   // absolute within-tag offset
    if (tid == 255) { dstart[256] = (unsigned)cb * BSTR_S + hist[255]; totS = hist[255]; }
    {   // within-quarter descending-degree rank (ties broken by index) -> perm
        int q0 = tid & ~63;
        int rank = 0;
        for (int j = 0; j < 64; ++j) {
            unsigned cj = cnt2[q0 + j];
            rank += (cj > c) || (cj == c && (q0 + j) < tid);
        }
        perm[q0 + rank] = (unsigned char)(tid & 63);
    }
    __syncthreads();
    for (unsigned i = tid; i < cnt; i += 256) {   // scatter into LDS sorted order
        unsigned w = in[i];
        unsigned r = atomicAdd(&cur[w >> 17], 1u);
        sbuf[r] = (w & 0x1FFFFu) << 3;            // pre-scaled uint4 row index
    }
    {
        const unsigned DUMMY = 0x80000000u | ((unsigned)(3 * N_NODES) << 3);
        for (unsigned k = c; k < pc; ++k) sbuf[excl + k] = DUMMY;  // disjoint slots
    }
    __syncthreads();
    unsigned tot = totS;                 // <= BSTR_S by construction
    for (unsigned i = tid; i < tot; i += 256) outp[i] = sbuf[i];
}

// ---------------- pack: head B-fragments (fp16) + transform weights + biases -----
__device__ __forceinline__ void pack_seg(
    const float* __restrict__ W, unsigned short* __restrict__ outp,
    int K, int O, int NKS, int idx)
{
    int f = idx >> 9, r = idx & 511;
    int l = r >> 3, j = r & 7;
    int ot = f / NKS, ks = f - ot * NKS;
    int k = ks * 32 + (l >> 4) * 8 + j;
    int o = ot * 16 + (l & 15);
    float val = (k < K && o < O) ? W[k * O + o] : 0.f;
    outp[idx] = __half_as_ushort(__float2half_rn(val));
}

__global__ __launch_bounds__(256) void pack_all_kernel(
    const float* __restrict__ projW, const float* __restrict__ W1,
    const float* __restrict__ W2, const float* __restrict__ W3,
    const float* __restrict__ b0, const float* __restrict__ b1,
    const float* __restrict__ b2, const float* __restrict__ b3,
    const float* __restrict__ Wl0, const float* __restrict__ Wr0,
    const float* __restrict__ Wl1, const float* __restrict__ Wr1,
    const float* __restrict__ Wl2, const float* __restrict__ Wr2,
    const float* __restrict__ bl0, const float* __restrict__ br0,
    const float* __restrict__ bl1, const float* __restrict__ br1,
    const float* __restrict__ bl2, const float* __restrict__ br2,
    unsigned short* __restrict__ wpkAll, float* __restrict__ biasPad,
    __half* __restrict__ xl3)
{
    int gid = blockIdx.x * 256 + threadIdx.x;
    if (gid < 25600) pack_seg(projW, wpkAll, 150, 150, 5, gid);
    else if (gid < 40960) pack_seg(W1, wpkAll + 25600, 150, 75, 5, gid - 25600);
    else if (gid < 44032) pack_seg(W2, wpkAll + 40960, 75, 30, 3, gid - 40960);
    else if (gid < 44544) pack_seg(W3, wpkAll + 44032, 30, 2, 1, gid - 44032);
    else if (gid < 56832) {
        int t = gid - 44544;
        int mat = t >> 11, idx = t & 2047;
        const float* Wm = (mat == 0) ? Wl0 : (mat == 1) ? Wr0 : (mat == 2) ? Wl1
                        : (mat == 3) ? Wr1 : (mat == 4) ? Wl2 : Wr2;
        int ot = idx >> 9, r = idx & 511;
        int l = r >> 3, j = r & 7;
        int k = (l >> 4) * 8 + j;
        int o = ot * 16 + (l & 15);
        float val = (k < D_IN && o < D_OUT) ? Wm[k * D_OUT + o] : 0.f;
        wpkAll[44544 + t] = __half_as_ushort(__float2half_rn(val));
    } else if (gid < 57520) {
        int t = gid - 56832;
        float v;
        if (t < 304) {
            if (t < 160) v = (t < 150) ? b0[t] : 0.f;
            else if (t < 256) { int i = t - 160; v = (i < 75) ? b1[i] : 0.f; }
            else if (t < 288) { int i = t - 256; v = (i < 30) ? b2[i] : 0.f; }
            else { int i = t - 288; v = (i < 2) ? b3[i] : 0.f; }
        } else {
            int ii = t - 304;
            int mat = ii >> 6, o = ii & 63;
            const float* bm = (mat == 0) ? bl0 : (mat == 1) ? br0 : (mat == 2) ? bl1
                            : (mat == 3) ? br1 : (mat == 4) ? bl2 : br2;
            v = (o < D_OUT) ? bm[o] : 0.f;
        }
        biasPad[t] = v;
    } else if (gid < 57584) {
        // zero row at absolute row 3*N_NODES: dummy-edge gather target
        xl3[(size_t)3 * N_NODES * 64 + (gid - 57520)] = __ushort_as_half((unsigned short)0);
    }
}

// ---------------- MFMA node transform: xl/xr (6 mats) via 16x16x32 f16 -----------
#define TSTR 32
#define OSTR 72

__global__ __launch_bounds__(256) void transform_mfma_kernel(
    const float* __restrict__ x,
    const unsigned short* __restrict__ wpkAll, const float* __restrict__ biasPad,
    __half* __restrict__ xl3, __half* __restrict__ xr3)
{
    __shared__ _Float16 sX[64 * TSTR];
    __shared__ _Float16 sO[4][16 * OSTR];
    int tid = threadIdx.x;
    int w = tid >> 6, l = tid & 63;
    int g0 = blockIdx.x * 64;
    for (int i = tid; i < 64 * D_IN; i += 256) {
        int r = i / D_IN, c = i - r * D_IN;
        int gr = g0 + r;
        sX[r * TSTR + c] = (gr < N_NODES) ? (_Float16)x[(size_t)gr * D_IN + c] : (_Float16)0.f;
    }
    for (int i = tid; i < 64 * 7; i += 256) {
        int r = i / 7, c = D_IN + (i - r * 7);
        sX[r * TSTR + c] = (_Float16)0.f;
    }
    __syncthreads();
    int lm = l & 15, q = l >> 4;
    half8 a = *(const half8*)(sX + (w * 16 + lm) * TSTR + q * 8);
    const unsigned short* wT = wpkAll + 44544;
#pragma unroll
    for (int mat = 0; mat < 6; ++mat) {
        float4v acc[4];
#pragma unroll
        for (int ot = 0; ot < 4; ++ot) {
            half8 b = *(const half8*)(wT + (mat * 4 + ot) * 512 + l * 8);
            float4v z = {0.f, 0.f, 0.f, 0.f};
            acc[ot] = __builtin_amdgcn_mfma_f32_16x16x32_f16(a, b, z, 0, 0, 0);
        }
#pragma unroll
        for (int ot = 0; ot < 4; ++ot) {
            float bv = biasPad[304 + mat * 64 + ot * 16 + lm];
#pragma unroll
            for (int r = 0; r < 4; ++r)
                sO[w][(q * 4 + r) * OSTR + ot * 16 + lm] = (_Float16)(acc[ot][r] + bv);
        }
        __half* dst = ((mat & 1) ? xr3 : xl3) + (size_t)(mat >> 1) * N_NODES * 64;
#pragma unroll
        for (int it = 0; it < 2; ++it) {
            int idx = it * 64 + l;
            int rr = idx >> 3, cc = idx & 7;
            int gr = g0 + w * 16 + rr;
            if (gr < N_NODES) {
                uint4 v = *(const uint4*)&sO[w][rr * OSTR + cc * 8];
                *(uint4*)&dst[(size_t)gr * 64 + cc * 8] = v;
            }
        }
    }
}

// ---------------- GATv2 aggregation over pre-sorted lists ------------------------
// One block per (64-dst group, tag). 48 VGPR — MUST stay <=64: crossing 64 halves
// the wave ceiling (round-6: 72 VGPR -> 29% occ, 145us). Degree-sorted stealing
// via permL; packed-f32 accumulation (round-8: 115 -> 110.5us).
__device__ __forceinline__ float edge_score8(uint4 u, const h2* xr, const h2* at)
{
    const h2 k2 = {(_Float16)0.2f, (_Float16)0.2f};
    float acc = 0.f;
    unsigned uu[4] = {u.x, u.y, u.z, u.w};
#pragma unroll
    for (int i = 0; i < 4; ++i) {
        h2 m = bch2(uu[i]) + xr[i];
        m = __builtin_elementwise_max(m, m * k2);
        acc = __builtin_amdgcn_fdot2(m, at[i], acc, false);
    }
    return acc;
}
__device__ __forceinline__ void accum8v(f2* O, float w, uint4 u)
{
    unsigned uu[4] = {u.x, u.y, u.z, u.w};
    f2 wv = {w, w};
#pragma unroll
    for (int i = 0; i < 4; ++i) {
        h2 xv = bch2(uu[i]);
        f2 xf = {(float)xv[0], (float)xv[1]};
        O[i] += wv * xf;                 // packed f32 fma
    }
}

__global__ __launch_bounds__(256) void bkt_gat_kernel(
    const unsigned* __restrict__ srcsS, const unsigned* __restrict__ dstartAll,
    const unsigned char* __restrict__ permAll,
    const __half* __restrict__ xl3, const __half* __restrict__ xr3,
    const float* __restrict__ att0, const float* __restrict__ att1, const float* __restrict__ att2,
    const float* __restrict__ bo0, const float* __restrict__ bo1, const float* __restrict__ bo2,
    __half* __restrict__ h16)
{
    int tag = blockIdx.y, fb = blockIdx.x;
    int cb = fb >> 2;                 // coarse bucket
    int qd = fb & 3;                  // quarter within coarse bucket
    const unsigned* srcs = srcsS + (size_t)tag * NBKT_C * BSTR_S;
    const unsigned* dstart = dstartAll + ((size_t)tag * NBKT_C + cb) * 257 + qd * 64;
    const uint4* xl4 = (const uint4*)xl3 + (size_t)tag * N_NODES * 8;
    const uint4* xr4 = (const uint4*)xr3 + (size_t)tag * N_NODES * 8;
    const float* att = (tag == 0) ? att0 : (tag == 1) ? att1 : att2;
    const float* bo  = (tag == 0) ? bo0  : (tag == 1) ? bo1  : bo2;
    int col0 = tag * 50;

    __shared__ unsigned nextD;
    __shared__ unsigned char permL[DPB];
    int tid = threadIdx.x;
    if (tid < DPB)
        permL[tid] = permAll[(((size_t)tag * NBKT_C + cb) << 8) + (qd << 6) + tid];
    if (tid == 0) nextD = 0;
    __syncthreads();

    // ---- aggregation: 32 groups x 8 lanes; work-stealing over the DPB dsts
    const int l = tid & 7;
    const int grpBase = tid & ~7;
    int c0 = 8 * l;
    h2 at[4];
#pragma unroll
    for (int i = 0; i < 4; ++i) {
        int cc = c0 + 2 * i;
        float lo = (cc < D_OUT) ? att[cc] : 0.f;
        float hi = (cc + 1 < D_OUT) ? att[cc + 1] : 0.f;
        at[i] = h2{(_Float16)lo, (_Float16)hi};
    }
    for (;;) {
        unsigned d;
        if (l == 0) d = atomicAdd(&nextD, 1u);
        d = (unsigned)__shfl((int)d, grpBase);
        if (d >= (unsigned)DPB) break;
        int pd = (int)permL[d];       // degree-sorted steal order
        int g = (cb << 8) + (qd << 6) + pd;
        if (g >= N_NODES) continue;   // tail guard
        uint4 xru = xr4[g * 8 + l];
        h2 xr[4] = {bch2(xru.x), bch2(xru.y), bch2(xru.z), bch2(xru.w)};
        uint4 xs = xl4[g * 8 + l];

        float q = edge_score8(xs, xr, at);
        q += __shfl_xor(q, 1); q += __shfl_xor(q, 2); q += __shfl_xor(q, 4);
        float S = __expf(q);                    // scores bounded: raw exp safe
        f2 O[4];
#pragma unroll
        for (int i = 0; i < 4; ++i) O[i] = f2{0.f, 0.f};
        accum8v(O, S, xs);

        unsigned j = dstart[pd], jE = dstart[pd + 1];
        if (j < jE) {
            uint4 vv = *(const uint4*)&srcs[j];        // 16B-aligned (j % 4 == 0)
            uint4 c0v = xl4[(vv.x & 0x7FFFFFFFu) + l];
            uint4 c1v = xl4[(vv.y & 0x7FFFFFFFu) + l];
            uint4 c2v = xl4[(vv.z & 0x7FFFFFFFu) + l];
            uint4 c3v = xl4[(vv.w & 0x7FFFFFFFu) + l];
            for (;;) {
                j += 4;
                bool more = j < jE;
                uint4 nv, p0v, p1v, p2v, p3v;
                if (more) {
                    nv = *(const uint4*)&srcs[j];
                    p0v = xl4[(nv.x & 0x7FFFFFFFu) + l];
                    p1v = xl4[(nv.y & 0x7FFFFFFFu) + l];
                    p2v = xl4[(nv.z & 0x7FFFFFFFu) + l];
                    p3v = xl4[(nv.w & 0x7FFFFFFFu) + l];
                }
                float p0 = edge_score8(c0v, xr, at);
                float p1 = edge_score8(c1v, xr, at);
                float p2 = edge_score8(c2v, xr, at);
                float p3 = edge_score8(c3v, xr, at);
                p0 += __shfl_xor(p0, 1); p0 += __shfl_xor(p0, 2); p0 += __shfl_xor(p0, 4);
                p1 += __shfl_xor(p1, 1); p1 += __shfl_xor(p1, 2); p1 += __shfl_xor(p1, 4);
                p2 += __shfl_xor(p2, 1); p2 += __shfl_xor(p2, 2); p2 += __shfl_xor(p2, 4);
                p3 += __shfl_xor(p3, 1); p3 += __shfl_xor(p3, 2); p3 += __shfl_xor(p3, 4);
                float w0 = (vv.x & 0x80000000u) ? 0.f : __expf(p0);
                float w1 = (vv.y & 0x80000000u) ? 0.f : __expf(p1);
                float w2 = (vv.z & 0x80000000u) ? 0.f : __expf(p2);
                float w3 = (vv.w & 0x80000000u) ? 0.f : __expf(p3);
                S += (w0 + w1) + (w2 + w3);
                accum8v(O, w0, c0v);
                accum8v(O, w1, c1v);
                accum8v(O, w2, c2v);
                accum8v(O, w3, c3v);
                if (!more) break;
                vv = nv; c0v = p0v; c1v = p1v; c2v = p2v; c3v = p3v;
            }
        }
        float inv = 1.f / (S + 1e-16f);
        size_t base = (size_t)g * 160 + col0 + c0;
#pragma unroll
        for (int i = 0; i < 4; ++i) {
            int cc = c0 + 2 * i;
            if (cc + 1 < D_OUT) {
                float blo = bo[cc], bhi = bo[cc + 1];
                float vlo = lrelu(O[i][0] * inv + blo, 0.1f);
                float vhi = lrelu(O[i][1] * inv + bhi, 0.1f);
                *(__half2*)&h16[base + 2 * i] = __floats2half2_rn(vlo, vhi);
            }
        }
    }
}

// ---------------- fused MFMA MLP head, wave-private single-buffer ----------------
// Each wave owns sBuf[w] (16 rows x HS) — no cross-wave sharing, so NO barriers:
// within a wave LDS ops are program-ordered and lanes run in lockstep, and each
// layer hoists its A fragments into registers BEFORE writing its output in place.
// LDS: 43KB (sIn+sOut) -> 21.5KB -> ~3 blocks/CU under the ~64KB effective LDS
// occupancy budget (rounds 1/2: 13.8/16.4KB blocks both capped at 4 blk/CU).
#define HS 168

template<int NOT, int NKS, bool ACT>
__device__ __forceinline__ void head_layer_ip(
    _Float16* buf, const unsigned short* __restrict__ wp,
    const float* __restrict__ bias, int l)
{
    const int lm = l & 15, q = l >> 4;
    half8 aR[NKS];
#pragma unroll
    for (int ks = 0; ks < NKS; ++ks)
        aR[ks] = *(const half8*)(buf + lm * HS + ks * 32 + q * 8);
#pragma unroll
    for (int ot = 0; ot < NOT; ++ot) {
        float4v acc = {0.f, 0.f, 0.f, 0.f};
        const unsigned short* bBase = wp + (ot * NKS) * 512 + l * 8;
#pragma unroll
        for (int ks = 0; ks < NKS; ++ks) {
            half8 b = *(const half8*)(bBase + ks * 512);
            acc = __builtin_amdgcn_mfma_f32_16x16x32_f16(aR[ks], b, acc, 0, 0, 0);
        }
        float bv = bias[ot * 16 + lm];
#pragma unroll
        for (int r = 0; r < 4; ++r) {
            float v = acc[r] + bv;
            if (ACT) v = lrelu(v, 0.1f);
            buf[(q * 4 + r) * HS + ot * 16 + lm] = (_Float16)v;
        }
    }
}

__global__ __launch_bounds__(256) void mfma_head_kernel(
    const __half* __restrict__ h16,
    const unsigned short* __restrict__ wpkAll, const float* __restrict__ biasPad,
    float* __restrict__ out)
{
    __shared__ _Float16 sBuf[4][16 * HS];
    int tid = threadIdx.x;
    int w = tid >> 6, l = tid & 63;
    int g0 = blockIdx.x * 64 + w * 16;
    _Float16* buf = sBuf[w];

    const uint2* hq = (const uint2*)h16;
    for (int idx = l; idx < 16 * 42; idx += 64) {
        int row = idx / 42, qc = idx - row * 42;
        int gn = g0 + row;
        uint2 u = {0u, 0u};
        if (gn < N_NODES && qc < 40) {
            u = hq[(size_t)gn * 40 + qc];
            if (qc == 37) u.y = 0u;
            else if (qc > 37) { u.x = 0u; u.y = 0u; }
        }
        *(uint2*)&buf[row * HS + qc * 4] = u;
    }
    // no __syncthreads anywhere: buffer is wave-private, LDS ops wave-ordered
    head_layer_ip<10, 5, false>(buf, wpkAll,         biasPad + 0,   l);  // 150->150
    head_layer_ip<6, 5, true >(buf, wpkAll + 25600,  biasPad + 160, l);  // 150->75
    head_layer_ip<2, 3, true >(buf, wpkAll + 40960,  biasPad + 256, l);  // 75->30
    {
        const int lm = l & 15, q = l >> 4;
        float4v acc = {0.f, 0.f, 0.f, 0.f};
        half8 a = *(const half8*)(buf + lm * HS + q * 8);
        half8 b = *(const half8*)(wpkAll + 44032 + l * 8);
        acc = __builtin_amdgcn_mfma_f32_16x16x32_f16(a, b, acc, 0, 0, 0);
        if (lm < 2) {
            float bv = biasPad[288 + lm];
#pragma unroll
            for (int r = 0; r < 4; ++r) {
                int node = g0 + q * 4 + r;
                if (node < N_NODES) out[node * 2 + lm] = acc[r] + bv;
            }
        }
    }
}

extern "C" void kernel_launch(void* const* d_in, const int* in_sizes, int n_in,
                              void* d_out, int out_size, void* d_ws, size_t ws_size,
                              hipStream_t stream)
{
    const float* x = (const float*)d_in[0];
    const int* eip = (const int*)d_in[1];
    const int* eis = (const int*)d_in[2];
    const int* eiv = (const int*)d_in[3];
    const float *Wl[3], *bl[3], *Wr[3], *br[3], *att[3], *bo[3];
    for (int t = 0; t < 3; ++t) {
        int b = 4 + t * 6;
        Wl[t] = (const float*)d_in[b + 0];
        bl[t] = (const float*)d_in[b + 1];
        Wr[t] = (const float*)d_in[b + 2];
        br[t] = (const float*)d_in[b + 3];
        att[t] = (const float*)d_in[b + 4];
        bo[t] = (const float*)d_in[b + 5];
    }
    const float* projW = (const float*)d_in[22];
    const float* projb = (const float*)d_in[23];
    const float* W1 = (const float*)d_in[24];
    const float* b1 = (const float*)d_in[25];
    const float* W2 = (const float*)d_in[26];
    const float* b2 = (const float*)d_in[27];
    const float* W3 = (const float*)d_in[28];
    const float* b3 = (const float*)d_in[29];
    float* out = (float*)d_out;

    char* ws = (char*)d_ws;
    size_t off = 0;
    auto alloc = [&](size_t bytes) -> char* {
        char* p = ws + off;
        off += (bytes + 255) & ~(size_t)255;
        return p;
    };
    // xl3 has one extra zero row at absolute row index 3*N_NODES (dummy target)
    __half* xl3 = (__half*)alloc(((size_t)3 * N_NODES * 64 + 64) * 2);  // 38.4 MB
    __half* xr3 = (__half*)alloc((size_t)3 * N_NODES * 64 * 2);         // 38.4 MB
    unsigned* bucketedC = (unsigned*)alloc((size_t)3 * NBKT_C * BSTR_C * 4); // 22.5 MB
    unsigned* bcur3 = (unsigned*)alloc((size_t)3 * NBKT_C * 4);
    unsigned* srcsS = (unsigned*)alloc((size_t)3 * NBKT_C * BSTR_S * 4); // 26.1 MB
    unsigned* dstartAll = (unsigned*)alloc((size_t)3 * NBKT_C * 257 * 4); // 1.2 MB
    unsigned char* permAll = (unsigned char*)alloc((size_t)3 * NBKT_C * 256); // 0.3 MB
    __half* h16 = (__half*)alloc((size_t)N_NODES * 160 * 2);            // 32 MB
    unsigned short* wpkAll = (unsigned short*)alloc(56832 * 2);
    float* biasPad = (float*)alloc(688 * 4);

    hipMemsetAsync(bcur3, 0, (size_t)3 * NBKT_C * 4, stream);
    pack_all_kernel<<<226, 256, 0, stream>>>(
        projW, W1, W2, W3, projb, b1, b2, b3,
        Wl[0], Wr[0], Wl[1], Wr[1], Wl[2], Wr[2],
        bl[0], br[0], bl[1], br[1], bl[2], br[2],
        wpkAll, biasPad, xl3);

    bkt_scatter_kernel<<<dim3(NBLK_E, 3), SCT_T, 0, stream>>>(eip, eis, eiv, bcur3, bucketedC);

    bkt_sort_kernel<<<dim3(NBKT_C, 3), 256, 0, stream>>>(bucketedC, bcur3, srcsS, dstartAll, permAll);

    transform_mfma_kernel<<<(N_NODES + 63) / 64, 256, 0, stream>>>(
        x, wpkAll, biasPad, xl3, xr3);

    bkt_gat_kernel<<<dim3(NBKT_F, 3), 256, 0, stream>>>(
        srcsS, dstartAll, permAll, xl3, xr3,
        att[0], att[1], att[2], bo[0], bo[1], bo[2], h16);

    mfma_head_kernel<<<(N_NODES + 63) / 64, 256, 0, stream>>>(h16, wpkAll, biasPad, out);
}